// Round 9
// baseline (599.520 us; speedup 1.0000x reference)
//
#include <hip/hip_runtime.h>
#include <cstdint>
#include <cstddef>

// Problem dims
#define NB 2
#define NTT 2048
#define ND 1024
#define NK 8
#define NF 4096
#define NTOK (NB*NTT)
#define LAMBDA_C 0.5f

// Output layout (float units)
#define Y_SZ   (NTOK*ND)
#define LG_OFF Y_SZ
#define SC_OFF (LG_OFF + NTOK*NK)
#define AD_OFF (SC_OFF + NK)

// Workspace layout (4-byte units)
#define WS_CNT    0
#define WS_SEG    8
#define WS_NTILES 17
#define WS_TILEK  32
#define WS_TILER  1056
#define WS_PTOK   4096
#define WS_PCOEF  36864
#define WS_COEF   69632
#define WS_X16    102400   // x as f16 (8MB)
#define WS_H      2199552  // f16 h buffer

#define BM 128
#define BN 128
#define BK 64
#define SPLITK2 4
#define KT 16

// LDS byte offsets: A dbuf 2x16KB, B dbuf 2x16KB
#define ASL0 0u
#define ASL1 16384u
#define BSL0 32768u
#define BSL1 49152u

typedef float  f32x4  __attribute__((ext_vector_type(4)));
typedef float  f32x16 __attribute__((ext_vector_type(16)));
typedef _Float16 f16x8 __attribute__((ext_vector_type(8)));
typedef unsigned int u32x4 __attribute__((ext_vector_type(4)));

__device__ __forceinline__ unsigned int pkrtz(float a, float b){
    auto h = __builtin_amdgcn_cvt_pkrtz(a, b);
    return __builtin_bit_cast(unsigned int, h);
}
__device__ __forceinline__ float gelu_exact(float v){
    return 0.5f * v * (1.0f + erff(v * 0.70710678118654752440f));
}

// ---------------- x -> f16 prepass ----------------
__global__ __launch_bounds__(256) void k_xcast(const float* __restrict__ x,
                                               unsigned short* __restrict__ x16)
{
    int i = (blockIdx.x*256 + threadIdx.x) * 16;
    const f32x4* src = (const f32x4*)(x + i);
    f32x4 v0 = src[0], v1 = src[1], v2 = src[2], v3 = src[3];
    u32x4 o0 = {pkrtz(v0[0],v0[1]), pkrtz(v0[2],v0[3]), pkrtz(v1[0],v1[1]), pkrtz(v1[2],v1[3])};
    u32x4 o1 = {pkrtz(v2[0],v2[1]), pkrtz(v2[2],v2[3]), pkrtz(v3[0],v3[1]), pkrtz(v3[2],v3[3])};
    *(u32x4*)(x16 + i)     = o0;
    *(u32x4*)(x16 + i + 8) = o1;
}

// ---------------- gating ----------------
__global__ __launch_bounds__(256) void k_gating(
    const float* __restrict__ x, const float* __restrict__ pl,
    const float* __restrict__ Wt, const float* __restrict__ Wgt,
    const float* __restrict__ Wel, float* __restrict__ out,
    float* __restrict__ coef, int* __restrict__ cnt)
{
    int t = blockIdx.x;
    const float* xt = x + (size_t)t * ND;
    float acc[NK] = {0,0,0,0,0,0,0,0};
    for (int d = threadIdx.x; d < ND; d += 256){
        float xv = xt[d];
        const float4* w = (const float4*)(Wt + (size_t)d * NK);
        float4 w0 = w[0], w1 = w[1];
        acc[0] += xv*w0.x; acc[1] += xv*w0.y; acc[2] += xv*w0.z; acc[3] += xv*w0.w;
        acc[4] += xv*w1.x; acc[5] += xv*w1.y; acc[6] += xv*w1.z; acc[7] += xv*w1.w;
    }
    __shared__ float red[4][NK];
    #pragma unroll
    for (int k = 0; k < NK; k++){
        float v = acc[k];
        #pragma unroll
        for (int off = 32; off; off >>= 1) v += __shfl_down(v, off);
        if ((threadIdx.x & 63) == 0) red[threadIdx.x >> 6][k] = v;
    }
    __syncthreads();
    if (threadIdx.x == 0){
        const float* p = pl + (size_t)t * NK;
        float pv[NK];
        #pragma unroll
        for (int j = 0; j < NK; j++) pv[j] = p[j];
        float lg[NK]; float mx = -1e30f;
        #pragma unroll
        for (int k = 0; k < NK; k++){
            float v = red[0][k] + red[1][k] + red[2][k] + red[3][k];
            #pragma unroll
            for (int j = 0; j < NK; j++) v += pv[j] * Wgt[j*NK + k];
            lg[k] = v; mx = fmaxf(mx, v);
            out[LG_OFF + (size_t)t*NK + k] = v;
        }
        float e[NK]; float s = 0.f;
        #pragma unroll
        for (int k = 0; k < NK; k++){ e[k] = expf(lg[k] - mx); s += e[k]; }
        float g[NK]; float gsum = 0.f;
        #pragma unroll
        for (int k = 0; k < NK; k++){
            float st = e[k] / s;
            float we = 1.f / (1.f + expf(-Wel[k]));
            bool m = st > LAMBDA_C * we;
            g[k] = m ? st : 0.f;
            gsum += g[k];
        }
        float inv = 1.f / (gsum + 1e-6f);
        #pragma unroll
        for (int k = 0; k < NK; k++){
            coef[(size_t)t*NK + k] = g[k] * inv;
            if (g[k] > 0.f) atomicAdd(&cnt[k], 1);
        }
    }
}

// ---------------- scan ----------------
__global__ __launch_bounds__(256) void k_scan(
    const float* __restrict__ coef, int* __restrict__ wsi,
    float* __restrict__ wsf, int pair_cap)
{
    int k = blockIdx.x;
    const int* cnt = wsi + WS_CNT;
    int base = 0;
    for (int j = 0; j < k; j++) base += cnt[j];
    int tid = threadIdx.x, lane = tid & 63, w = tid >> 6;
    __shared__ int wsum[4];
    __shared__ int sbase;
    if (tid == 0){
        sbase = base;
        wsi[WS_SEG + k] = base;
        if (k == NK-1) wsi[WS_SEG + NK] = base + cnt[k];
    }
    __syncthreads();
    int* ptok = wsi + WS_PTOK;
    float* pc = wsf + WS_PCOEF;
    for (int c0 = 0; c0 < NTOK; c0 += 256){
        int t = c0 + tid;
        float c = coef[(size_t)t*NK + k];
        bool m = c > 0.f;
        unsigned long long bal = __ballot(m);
        int pre = __popcll(bal & ((1ull << lane) - 1ull));
        if (lane == 0) wsum[w] = __popcll(bal);
        __syncthreads();
        int b = sbase;
        for (int j = 0; j < w; j++) b += wsum[j];
        if (m){
            int pos = b + pre;
            if (pos < pair_cap){ ptok[pos] = t; pc[pos] = c; }
        }
        __syncthreads();
        if (tid == 0) sbase += wsum[0] + wsum[1] + wsum[2] + wsum[3];
        __syncthreads();
    }
}

// ---------------- tiles + small outputs ----------------
__global__ void k_tiles(int* __restrict__ wsi, float* __restrict__ out, int pair_cap)
{
    if (threadIdx.x == 0 && blockIdx.x == 0){
        const int* cnt = wsi + WS_CNT;
        const int* seg = wsi + WS_SEG;
        int total = 0;
        for (int k = 0; k < NK; k++){ total += cnt[k]; out[SC_OFF + k] = (float)cnt[k]; }
        out[AD_OFF] = (float)total / (float)NTOK;
        int nt = 0;
        for (int k = 0; k < NK; k++){
            int e = min(seg[k+1], pair_cap);
            for (int r = seg[k]; r < e; r += BM){
                wsi[WS_TILEK + nt] = k; wsi[WS_TILER + nt] = r; nt++;
            }
        }
        wsi[WS_NTILES] = nt;
    }
}

// XCD-chunked bijective work partition
#define XCD_PART_LOOP(nwork)                                              \
    int q_ = (nwork) >> 3, rr_ = (nwork) & 7;                             \
    int xcd_ = blockIdx.x & 7;                                            \
    int slot_ = blockIdx.x >> 3;                                          \
    int nslot_ = gridDim.x >> 3;                                          \
    int cntw_ = q_ + (xcd_ < rr_ ? 1 : 0);                                \
    int start_ = xcd_ * q_ + (xcd_ < rr_ ? xcd_ : rr_);                   \
    for (int p_ = slot_; p_ < cntw_; p_ += nslot_)

// ---- shared GEMM building blocks ----
// B LDS: col c (0..127) at c*128B; k-octet u (16B) at (u*16)^(((c>>2)&7)<<4)
// A LDS: row r (0..127) at r*128B; 16B slot v at (v*16)^((r&7)<<4); filled by
//        global_load_lds with pre-swizzled per-lane SOURCE (LDS linear dest).

#define LOADB(G_, tt_, LDW_)                                              \
  { const float* bn_ = bsrc + (size_t)((tt_)*BK + bu*8)*(LDW_);           \
    _Pragma("unroll")                                                     \
    for (int r9_ = 0; r9_ < 8; r9_++) G_[r9_] = *(const f32x4*)(bn_ + (size_t)r9_*(LDW_)); }

#define CVTWRB(G_, BO_)                                                   \
  { _Pragma("unroll")                                                     \
    for (int j9_ = 0; j9_ < 4; j9_++){                                    \
        unsigned p0_ = pkrtz(G_[0][j9_], G_[1][j9_]);                     \
        unsigned p1_ = pkrtz(G_[2][j9_], G_[3][j9_]);                     \
        unsigned p2_ = pkrtz(G_[4][j9_], G_[5][j9_]);                     \
        unsigned p3_ = pkrtz(G_[6][j9_], G_[7][j9_]);                     \
        unsigned c9_ = (unsigned)(bg*4 + j9_);                            \
        unsigned off9_ = (BO_) + c9_*128u + (((unsigned)bu*16u) ^ (((c9_>>2)&7u)<<4)); \
        *(u32x4*)(&lds[off9_]) = (u32x4){p0_, p1_, p2_, p3_};             \
    } }

#define GLL_A(AO_, tt_)                                                   \
  { _Pragma("unroll")                                                     \
    for (int c9_ = 0; c9_ < 4; c9_++){                                    \
        const unsigned short* g9_ = asrc[c9_] + (tt_)*BK + asw8;          \
        __builtin_amdgcn_global_load_lds(                                 \
            (const __attribute__((address_space(1))) void*)g9_,           \
            (__attribute__((address_space(3))) void*)(&lds[(AO_) + (unsigned)((wv*4 + c9_)*1024)]), \
            16, 0, 0);                                                    \
    } }

#define MFMA_PH(AO_, BO_)                                                 \
  { __builtin_amdgcn_s_setprio(1);                                        \
    _Pragma("unroll")                                                     \
    for (int s9_ = 0; s9_ < 4; s9_++){                                    \
        unsigned ko_ = (unsigned)(s9_*32) + ah16;                         \
        f16x8 a0_ = *(const f16x8*)(&lds[(AO_) + arow0*128u + (ko_ ^ axr)]); \
        f16x8 a1_ = *(const f16x8*)(&lds[(AO_) + arow1*128u + (ko_ ^ axr)]); \
        f16x8 b0_ = *(const f16x8*)(&lds[(BO_) + bcol0*128u + (ko_ ^ bxr)]); \
        f16x8 b1_ = *(const f16x8*)(&lds[(BO_) + bcol1*128u + (ko_ ^ bxr)]); \
        acc00 = __builtin_amdgcn_mfma_f32_32x32x16_f16(a0_, b0_, acc00, 0,0,0); \
        acc01 = __builtin_amdgcn_mfma_f32_32x32x16_f16(a0_, b1_, acc01, 0,0,0); \
        acc10 = __builtin_amdgcn_mfma_f32_32x32x16_f16(a1_, b0_, acc10, 0,0,0); \
        acc11 = __builtin_amdgcn_mfma_f32_32x32x16_f16(a1_, b1_, acc11, 0,0,0); \
    }                                                                     \
    __builtin_amdgcn_s_setprio(0); }

// Depth-2 pipeline. Loop invariant at iter entry (per-thread vmem FIFO):
//   [gen_t(8), GLL_slot(4), gen_{t+1}(8)] = 20 outstanding.
//   vmcnt(12) drains exactly gen_t; vmcnt(8) drains exactly own GLL_slot;
//   gen_{t+1} stays in flight across the barrier (T4 counted-vmcnt).
#define PIPE_BODY(G_, AS_, BS_, AN_, tt_, LDW_)                           \
    asm volatile("s_waitcnt vmcnt(12)" ::: "memory");                     \
    CVTWRB(G_, BS_)                                                       \
    asm volatile("s_waitcnt vmcnt(8) lgkmcnt(0)" ::: "memory");           \
    __builtin_amdgcn_s_barrier();                                         \
    __builtin_amdgcn_sched_barrier(0);                                    \
    GLL_A(AN_, (tt_)+1)                                                   \
    if ((tt_) + 2 < KT){ LOADB(G_, (tt_)+2, LDW_) }                       \
    MFMA_PH(AS_, BS_)

#define PIPE_LOOP(LDW_)                                                   \
    f32x16 acc00 = {0}, acc01 = {0}, acc10 = {0}, acc11 = {0};            \
    f32x4 genA[8], genB[8];                                               \
    LOADB(genA, 0, LDW_)                                                  \
    LOADB(genB, 1, LDW_)                                                  \
    GLL_A(ASL0, 0)                                                        \
    for (int t = 0; t < KT-1; t++){                                       \
        if ((t & 1) == 0){ PIPE_BODY(genA, ASL0, BSL0, ASL1, t, LDW_) }   \
        else             { PIPE_BODY(genB, ASL1, BSL1, ASL0, t, LDW_) }   \
    }                                                                     \
    /* t = KT-1 (odd): outstanding = [genB(8), GLL_ASL1(4)] */            \
    asm volatile("s_waitcnt vmcnt(4)" ::: "memory");                      \
    CVTWRB(genB, BSL1)                                                    \
    asm volatile("s_waitcnt vmcnt(0) lgkmcnt(0)" ::: "memory");           \
    __builtin_amdgcn_s_barrier();                                         \
    __builtin_amdgcn_sched_barrier(0);                                    \
    MFMA_PH(ASL1, BSL1)

// ---------------- GEMM1: h = gelu(gather(x16) @ W1[k] + b1[k]) ----------------
__global__ __launch_bounds__(256, 2) void k_gemm1(
    const unsigned short* __restrict__ x16, const float* __restrict__ W1,
    const float* __restrict__ b1, const int* __restrict__ wsi,
    unsigned short* __restrict__ hbuf, int pair_cap)
{
    __shared__ char lds[65536];
    __shared__ int stok[BM];
    const int* seg  = wsi + WS_SEG;
    const int* tk   = wsi + WS_TILEK;
    const int* tr   = wsi + WS_TILER;
    const int* ptok = wsi + WS_PTOK;
    int ntm = wsi[WS_NTILES];
    int nwork = ntm * (NF / BN);
    int tid  = threadIdx.x;
    int L    = tid & 63;
    int wv   = tid >> 6;
    int wr = wv >> 1, wc = wv & 1;
    int bu = tid & 7, bg = tid >> 3;           // B staging roles (conflict-balanced)
    unsigned l31 = (unsigned)(L & 31);
    unsigned arow0 = (unsigned)(wr*64) + l31;
    unsigned arow1 = arow0 + 32u;
    unsigned bcol0 = (unsigned)(wc*64) + l31;
    unsigned bcol1 = bcol0 + 32u;
    unsigned ah16 = (unsigned)((L >> 5) * 16);
    unsigned axr  = (unsigned)((L & 7) << 4);
    unsigned bxr  = ((l31 >> 2) & 7u) << 4;
    int asw8 = ((L & 7) ^ (L >> 3)) * 8;       // pre-swizzled source (f16 units)
    int srow = L >> 3;

    XCD_PART_LOOP(nwork){
        int widx = start_ + p_;
        int mt = widx % ntm;
        int ft = widx / ntm;
        int kexp = tk[mt];
        int row0 = tr[mt];
        int nrows = min(BM, seg[kexp+1] - row0);
        int f0 = ft * BN;
        __syncthreads();
        if (tid < BM){
            int r = row0 + tid;
            stok[tid] = (tid < nrows && r < pair_cap) ? ptok[r] : ptok[row0];
        }
        __syncthreads();
        const unsigned short* asrc[4];
        #pragma unroll
        for (int c = 0; c < 4; c++)
            asrc[c] = x16 + (size_t)stok[(wv*4 + c)*8 + srow] * ND;
        const float* bsrc = W1 + (size_t)kexp*ND*NF + f0 + bg*4;
        PIPE_LOOP(NF)
        // epilogue
        const float* b1k = b1 + (size_t)kexp*NF;
        #pragma unroll
        for (int n = 0; n < 2; n++){
            int f = f0 + wc*64 + n*32 + (int)l31;
            float bv = b1k[f];
            #pragma unroll
            for (int m = 0; m < 2; m++){
                int rbase = wr*64 + m*32 + 4*(L>>5);
                const f32x16& a = (m==0) ? (n==0 ? acc00 : acc01) : (n==0 ? acc10 : acc11);
                #pragma unroll
                for (int rg = 0; rg < 16; rg++){
                    int row = rbase + (rg&3) + 8*(rg>>2);
                    if (row < nrows && row0 + row < pair_cap){
                        float v = gelu_exact(a[rg] + bv);
                        hbuf[(size_t)(row0+row)*NF + f] = (unsigned short)(pkrtz(v, 0.f) & 0xffffu);
                    }
                }
            }
        }
    }
}

// ---------------- GEMM2 (split-K): y += coef*(h @ W2[k] + b2[k]) ----------------
__global__ __launch_bounds__(256, 2) void k_gemm2(
    const unsigned short* __restrict__ hbuf, const float* __restrict__ W2,
    const float* __restrict__ b2, const int* __restrict__ wsi,
    const float* __restrict__ wsf, float* __restrict__ out, int pair_cap)
{
    __shared__ char lds[65536];
    __shared__ int stok[BM];
    __shared__ float scoef[BM];
    const int* seg  = wsi + WS_SEG;
    const int* tk   = wsi + WS_TILEK;
    const int* tr   = wsi + WS_TILER;
    const int* ptok = wsi + WS_PTOK;
    const float* pcoef = wsf + WS_PCOEF;
    int ntm = wsi[WS_NTILES];
    int nwork = ntm * (ND / BN) * SPLITK2;     // mt fastest, dt(8), sp(4)
    int tid  = threadIdx.x;
    int L    = tid & 63;
    int wv   = tid >> 6;
    int wr = wv >> 1, wc = wv & 1;
    int bu = tid & 7, bg = tid >> 3;
    unsigned l31 = (unsigned)(L & 31);
    unsigned arow0 = (unsigned)(wr*64) + l31;
    unsigned arow1 = arow0 + 32u;
    unsigned bcol0 = (unsigned)(wc*64) + l31;
    unsigned bcol1 = bcol0 + 32u;
    unsigned ah16 = (unsigned)((L >> 5) * 16);
    unsigned axr  = (unsigned)((L & 7) << 4);
    unsigned bxr  = ((l31 >> 2) & 7u) << 4;
    int asw8 = ((L & 7) ^ (L >> 3)) * 8;
    int srow = L >> 3;

    XCD_PART_LOOP(nwork){
        int widx = start_ + p_;
        int mt = widx % ntm;
        int rest = widx / ntm;
        int dt = rest & 7;
        int spk = rest >> 3;
        int kexp = tk[mt];
        int row0 = tr[mt];
        int nrows = min(BM, seg[kexp+1] - row0);
        int d0 = dt * BN;
        __syncthreads();
        if (tid < BM){
            int r = row0 + tid;
            bool v = (tid < nrows && r < pair_cap);
            stok[tid]  = v ? ptok[r] : 0;
            scoef[tid] = v ? pcoef[r] : 0.f;
        }
        __syncthreads();
        const unsigned short* asrc[4];
        #pragma unroll
        for (int c = 0; c < 4; c++){
            int rg = row0 + (wv*4 + c)*8 + srow;
            if (rg >= pair_cap) rg = pair_cap - 1;
            asrc[c] = hbuf + (size_t)rg*NF + spk*(NF/SPLITK2);
        }
        const float* bsrc = W2 + (size_t)kexp*NF*ND + (size_t)spk*(NF/SPLITK2)*ND + d0 + bg*4;
        PIPE_LOOP(ND)
        // epilogue
        const float* b2k = b2 + (size_t)kexp*ND;
        #pragma unroll
        for (int n = 0; n < 2; n++){
            int d = d0 + wc*64 + n*32 + (int)l31;
            float bv = (spk == 0) ? b2k[d] : 0.f;
            #pragma unroll
            for (int m = 0; m < 2; m++){
                int rbase = wr*64 + m*32 + 4*(L>>5);
                const f32x16& a = (m==0) ? (n==0 ? acc00 : acc01) : (n==0 ? acc10 : acc11);
                #pragma unroll
                for (int rg = 0; rg < 16; rg++){
                    int row = rbase + (rg&3) + 8*(rg>>2);
                    if (row < nrows && row0 + row < pair_cap){
                        float c = scoef[row];
                        atomicAdd(&out[(size_t)stok[row]*ND + d], c * (a[rg] + bv));
                    }
                }
            }
        }
    }
}

extern "C" void kernel_launch(void* const* d_in, const int* in_sizes, int n_in,
                              void* d_out, int out_size, void* d_ws, size_t ws_size,
                              hipStream_t stream)
{
    const float* x   = (const float*)d_in[0];
    const float* pl  = (const float*)d_in[1];
    const float* Wt  = (const float*)d_in[2];
    const float* Wgt = (const float*)d_in[3];
    const float* Wel = (const float*)d_in[4];
    const float* W1  = (const float*)d_in[5];
    const float* b1  = (const float*)d_in[6];
    const float* W2  = (const float*)d_in[7];
    const float* b2  = (const float*)d_in[8];
    float* out = (float*)d_out;
    int* wsi   = (int*)d_ws;
    float* wsf = (float*)d_ws;
    unsigned short* x16  = (unsigned short*)((char*)d_ws + (size_t)WS_X16*4);
    unsigned short* hbuf = (unsigned short*)((char*)d_ws + (size_t)WS_H*4);

    long long avail = (long long)ws_size - (long long)WS_H*4;
    long long cap = avail / ((long long)NF*2);
    if (cap > (long long)NTOK*NK) cap = (long long)NTOK*NK;
    if (cap < 0) cap = 0;
    int pair_cap = (int)cap;

    hipMemsetAsync(d_out, 0, (size_t)out_size*sizeof(float), stream);
    hipMemsetAsync(d_ws, 0, 32, stream);
    k_xcast<<<1024, 256, 0, stream>>>(x, x16);
    k_gating<<<NTOK, 256, 0, stream>>>(x, pl, Wt, Wgt, Wel, out, wsf + WS_COEF, wsi + WS_CNT);
    if (pair_cap > 0){
        k_scan<<<NK, 256, 0, stream>>>(wsf + WS_COEF, wsi, wsf, pair_cap);
        k_tiles<<<1, 64, 0, stream>>>(wsi, out, pair_cap);
        k_gemm1<<<2048, 256, 0, stream>>>(x16, W1, b1, wsi, hbuf, pair_cap);
        k_gemm2<<<2048, 256, 0, stream>>>(hbuf, W2, b2, wsi, wsf, out, pair_cap);
    }
}

// Round 10
// 542.845 us; speedup vs baseline: 1.1044x; 1.1044x over previous
//
#include <hip/hip_runtime.h>
#include <cstdint>
#include <cstddef>

// Problem dims
#define NB 2
#define NTT 2048
#define ND 1024
#define NK 8
#define NF 4096
#define NTOK (NB*NTT)
#define LAMBDA_C 0.5f

// Output layout (float units)
#define Y_SZ   (NTOK*ND)
#define LG_OFF Y_SZ
#define SC_OFF (LG_OFF + NTOK*NK)
#define AD_OFF (SC_OFF + NK)

// Workspace layout (4-byte units)
#define WS_CNT    0
#define WS_SEG    8
#define WS_NTILES 17
#define WS_TILEK  32
#define WS_TILER  1056
#define WS_PTOK   4096
#define WS_PCOEF  36864
#define WS_COEF   69632
#define WS_X16    102400   // x as f16 (8MB)
#define WS_H      2199552  // f16 h buffer

#define BM 128
#define BN 128
#define BK 64
#define SPLITK2 4
#define KT 16

// LDS byte offsets: A dbuf 2x16KB, B dbuf 2x16KB
#define ASL0 0u
#define ASL1 16384u
#define BSL0 32768u
#define BSL1 49152u

typedef float  f32x2  __attribute__((ext_vector_type(2)));
typedef float  f32x4  __attribute__((ext_vector_type(4)));
typedef float  f32x16 __attribute__((ext_vector_type(16)));
typedef _Float16 f16x8 __attribute__((ext_vector_type(8)));
typedef unsigned int u32x4 __attribute__((ext_vector_type(4)));

__device__ __forceinline__ unsigned int pkrtz(float a, float b){
    auto h = __builtin_amdgcn_cvt_pkrtz(a, b);
    return __builtin_bit_cast(unsigned int, h);
}
__device__ __forceinline__ float gelu_exact(float v){
    return 0.5f * v * (1.0f + erff(v * 0.70710678118654752440f));
}

// ---------------- x -> f16 prepass ----------------
__global__ __launch_bounds__(256) void k_xcast(const float* __restrict__ x,
                                               unsigned short* __restrict__ x16)
{
    int i = (blockIdx.x*256 + threadIdx.x) * 16;
    const f32x4* src = (const f32x4*)(x + i);
    f32x4 v0 = src[0], v1 = src[1], v2 = src[2], v3 = src[3];
    u32x4 o0 = {pkrtz(v0[0],v0[1]), pkrtz(v0[2],v0[3]), pkrtz(v1[0],v1[1]), pkrtz(v1[2],v1[3])};
    u32x4 o1 = {pkrtz(v2[0],v2[1]), pkrtz(v2[2],v2[3]), pkrtz(v3[0],v3[1]), pkrtz(v3[2],v3[3])};
    *(u32x4*)(x16 + i)     = o0;
    *(u32x4*)(x16 + i + 8) = o1;
}

// ---------------- gating ----------------
__global__ __launch_bounds__(256) void k_gating(
    const float* __restrict__ x, const float* __restrict__ pl,
    const float* __restrict__ Wt, const float* __restrict__ Wgt,
    const float* __restrict__ Wel, float* __restrict__ out,
    float* __restrict__ coef, int* __restrict__ cnt)
{
    int t = blockIdx.x;
    const float* xt = x + (size_t)t * ND;
    float acc[NK] = {0,0,0,0,0,0,0,0};
    for (int d = threadIdx.x; d < ND; d += 256){
        float xv = xt[d];
        const float4* w = (const float4*)(Wt + (size_t)d * NK);
        float4 w0 = w[0], w1 = w[1];
        acc[0] += xv*w0.x; acc[1] += xv*w0.y; acc[2] += xv*w0.z; acc[3] += xv*w0.w;
        acc[4] += xv*w1.x; acc[5] += xv*w1.y; acc[6] += xv*w1.z; acc[7] += xv*w1.w;
    }
    __shared__ float red[4][NK];
    #pragma unroll
    for (int k = 0; k < NK; k++){
        float v = acc[k];
        #pragma unroll
        for (int off = 32; off; off >>= 1) v += __shfl_down(v, off);
        if ((threadIdx.x & 63) == 0) red[threadIdx.x >> 6][k] = v;
    }
    __syncthreads();
    if (threadIdx.x == 0){
        const float* p = pl + (size_t)t * NK;
        float pv[NK];
        #pragma unroll
        for (int j = 0; j < NK; j++) pv[j] = p[j];
        float lg[NK]; float mx = -1e30f;
        #pragma unroll
        for (int k = 0; k < NK; k++){
            float v = red[0][k] + red[1][k] + red[2][k] + red[3][k];
            #pragma unroll
            for (int j = 0; j < NK; j++) v += pv[j] * Wgt[j*NK + k];
            lg[k] = v; mx = fmaxf(mx, v);
            out[LG_OFF + (size_t)t*NK + k] = v;
        }
        float e[NK]; float s = 0.f;
        #pragma unroll
        for (int k = 0; k < NK; k++){ e[k] = expf(lg[k] - mx); s += e[k]; }
        float g[NK]; float gsum = 0.f;
        #pragma unroll
        for (int k = 0; k < NK; k++){
            float st = e[k] / s;
            float we = 1.f / (1.f + expf(-Wel[k]));
            bool m = st > LAMBDA_C * we;
            g[k] = m ? st : 0.f;
            gsum += g[k];
        }
        float inv = 1.f / (gsum + 1e-6f);
        #pragma unroll
        for (int k = 0; k < NK; k++){
            coef[(size_t)t*NK + k] = g[k] * inv;
            if (g[k] > 0.f) atomicAdd(&cnt[k], 1);
        }
    }
}

// ---------------- scan ----------------
__global__ __launch_bounds__(256) void k_scan(
    const float* __restrict__ coef, int* __restrict__ wsi,
    float* __restrict__ wsf, int pair_cap)
{
    int k = blockIdx.x;
    const int* cnt = wsi + WS_CNT;
    int base = 0;
    for (int j = 0; j < k; j++) base += cnt[j];
    int tid = threadIdx.x, lane = tid & 63, w = tid >> 6;
    __shared__ int wsum[4];
    __shared__ int sbase;
    if (tid == 0){
        sbase = base;
        wsi[WS_SEG + k] = base;
        if (k == NK-1) wsi[WS_SEG + NK] = base + cnt[k];
    }
    __syncthreads();
    int* ptok = wsi + WS_PTOK;
    float* pc = wsf + WS_PCOEF;
    for (int c0 = 0; c0 < NTOK; c0 += 256){
        int t = c0 + tid;
        float c = coef[(size_t)t*NK + k];
        bool m = c > 0.f;
        unsigned long long bal = __ballot(m);
        int pre = __popcll(bal & ((1ull << lane) - 1ull));
        if (lane == 0) wsum[w] = __popcll(bal);
        __syncthreads();
        int b = sbase;
        for (int j = 0; j < w; j++) b += wsum[j];
        if (m){
            int pos = b + pre;
            if (pos < pair_cap){ ptok[pos] = t; pc[pos] = c; }
        }
        __syncthreads();
        if (tid == 0) sbase += wsum[0] + wsum[1] + wsum[2] + wsum[3];
        __syncthreads();
    }
}

// ---------------- tiles + small outputs ----------------
__global__ void k_tiles(int* __restrict__ wsi, float* __restrict__ out, int pair_cap)
{
    if (threadIdx.x == 0 && blockIdx.x == 0){
        const int* cnt = wsi + WS_CNT;
        const int* seg = wsi + WS_SEG;
        int total = 0;
        for (int k = 0; k < NK; k++){ total += cnt[k]; out[SC_OFF + k] = (float)cnt[k]; }
        out[AD_OFF] = (float)total / (float)NTOK;
        int nt = 0;
        for (int k = 0; k < NK; k++){
            int e = min(seg[k+1], pair_cap);
            for (int r = seg[k]; r < e; r += BM){
                wsi[WS_TILEK + nt] = k; wsi[WS_TILER + nt] = r; nt++;
            }
        }
        wsi[WS_NTILES] = nt;
    }
}

// XCD-chunked bijective work partition
#define XCD_PART_LOOP(nwork)                                              \
    int q_ = (nwork) >> 3, rr_ = (nwork) & 7;                             \
    int xcd_ = blockIdx.x & 7;                                            \
    int slot_ = blockIdx.x >> 3;                                          \
    int nslot_ = gridDim.x >> 3;                                          \
    int cntw_ = q_ + (xcd_ < rr_ ? 1 : 0);                                \
    int start_ = xcd_ * q_ + (xcd_ < rr_ ? xcd_ : rr_);                   \
    for (int p_ = slot_; p_ < cntw_; p_ += nslot_)

// ---- shared GEMM building blocks (512 threads / 8 waves) ----
// A slot: row r (0..127) at r*128B; 16B granule g at (g*16)^((r&7)<<4);
//         filled by global_load_lds, 2 issues/wave, pre-swizzled source.
// B slot: col c (0..127) at c*128B; k-octet u (16B) at (u*16)^(((c>>1)&7)<<4).
// B staging: thread owns cols {2*(tid&63), +1}, k-octet u = wave id. Loads are
//            8 x f32x2, each 512B-contiguous across the 64 lanes of a wave.

#define LOADB(G_, tt_, LDW_)                                              \
  { const float* bn_ = bsrc + (size_t)((tt_)*BK + wv*8)*(LDW_);           \
    _Pragma("unroll")                                                     \
    for (int j9_ = 0; j9_ < 8; j9_++) G_[j9_] = *(const f32x2*)(bn_ + (size_t)j9_*(LDW_)); }

#define CVTWRB(G_, BO_)                                                   \
  { unsigned a0_ = pkrtz(G_[0][0], G_[1][0]);                             \
    unsigned a1_ = pkrtz(G_[2][0], G_[3][0]);                             \
    unsigned a2_ = pkrtz(G_[4][0], G_[5][0]);                             \
    unsigned a3_ = pkrtz(G_[6][0], G_[7][0]);                             \
    unsigned b0_ = pkrtz(G_[0][1], G_[1][1]);                             \
    unsigned b1_ = pkrtz(G_[2][1], G_[3][1]);                             \
    unsigned b2_ = pkrtz(G_[4][1], G_[5][1]);                             \
    unsigned b3_ = pkrtz(G_[6][1], G_[7][1]);                             \
    *(u32x4*)(&lds[(BO_) + boff0]) = (u32x4){a0_, a1_, a2_, a3_};         \
    *(u32x4*)(&lds[(BO_) + boff0 + 128u]) = (u32x4){b0_, b1_, b2_, b3_};  \
  }

#define GLL_A(AO_, tt_)                                                   \
  { _Pragma("unroll")                                                     \
    for (int c9_ = 0; c9_ < 2; c9_++){                                    \
        const unsigned short* g9_ = asrc[c9_] + (tt_)*BK + asw8;          \
        __builtin_amdgcn_global_load_lds(                                 \
            (const __attribute__((address_space(1))) void*)g9_,           \
            (__attribute__((address_space(3))) void*)(&lds[(AO_) + (unsigned)((wv*2 + c9_)*1024)]), \
            16, 0, 0);                                                    \
    } }

#define MFMA_PH(AO_, BO_)                                                 \
  { __builtin_amdgcn_s_setprio(1);                                        \
    _Pragma("unroll")                                                     \
    for (int s9_ = 0; s9_ < 4; s9_++){                                    \
        unsigned ko_ = (unsigned)(s9_*32) + hi16;                         \
        f16x8 a_  = *(const f16x8*)(&lds[(AO_) + arowb + (ko_ ^ arkey)]); \
        f16x8 b0_ = *(const f16x8*)(&lds[(BO_) + bcolb + (ko_ ^ brkey)]); \
        f16x8 b1_ = *(const f16x8*)(&lds[(BO_) + bcolb + 4096u + (ko_ ^ brkey)]); \
        acc0 = __builtin_amdgcn_mfma_f32_32x32x16_f16(a_, b0_, acc0, 0,0,0); \
        acc1 = __builtin_amdgcn_mfma_f32_32x32x16_f16(a_, b1_, acc1, 0,0,0); \
    }                                                                     \
    __builtin_amdgcn_s_setprio(0); }

// Depth-2 pipeline, per-thread vmem FIFO at iter entry:
//   [gen_t(8), GLL_t(2), gen_{t+1}(8)] = 18 outstanding.
//   vmcnt(10) drains exactly gen_t; vmcnt(8) drains exactly GLL_t;
//   gen_{t+1} stays in flight across the barrier.
#define PIPE_BODY(G_, AS_, BS_, AN_, tt_, LDW_)                           \
    asm volatile("s_waitcnt vmcnt(10)" ::: "memory");                     \
    CVTWRB(G_, BS_)                                                       \
    asm volatile("s_waitcnt vmcnt(8) lgkmcnt(0)" ::: "memory");           \
    __builtin_amdgcn_s_barrier();                                         \
    __builtin_amdgcn_sched_barrier(0);                                    \
    GLL_A(AN_, (tt_)+1)                                                   \
    if ((tt_) + 2 < KT){ LOADB(G_, (tt_)+2, LDW_) }                       \
    MFMA_PH(AS_, BS_)

#define PIPE_LOOP(LDW_)                                                   \
    f32x16 acc0 = {0}, acc1 = {0};                                        \
    f32x2 genA[8], genB[8];                                               \
    LOADB(genA, 0, LDW_)                                                  \
    GLL_A(ASL0, 0)                                                        \
    LOADB(genB, 1, LDW_)                                                  \
    for (int t = 0; t < KT-1; t++){                                       \
        if ((t & 1) == 0){ PIPE_BODY(genA, ASL0, BSL0, ASL1, t, LDW_) }   \
        else             { PIPE_BODY(genB, ASL1, BSL1, ASL0, t, LDW_) }   \
    }                                                                     \
    /* t = KT-1 (odd): outstanding = [genB(8), GLL_ASL1(2)] */            \
    asm volatile("s_waitcnt vmcnt(2)" ::: "memory");                      \
    CVTWRB(genB, BSL1)                                                    \
    asm volatile("s_waitcnt vmcnt(0) lgkmcnt(0)" ::: "memory");           \
    __builtin_amdgcn_s_barrier();                                         \
    __builtin_amdgcn_sched_barrier(0);                                    \
    MFMA_PH(ASL1, BSL1)

// ---------------- GEMM1: h = gelu(gather(x16) @ W1[k] + b1[k]) ----------------
__global__ __launch_bounds__(512, 4) void k_gemm1(
    const unsigned short* __restrict__ x16, const float* __restrict__ W1,
    const float* __restrict__ b1, const int* __restrict__ wsi,
    unsigned short* __restrict__ hbuf, int pair_cap)
{
    __shared__ char lds[65536];
    __shared__ int stok[BM];
    const int* seg  = wsi + WS_SEG;
    const int* tk   = wsi + WS_TILEK;
    const int* tr   = wsi + WS_TILER;
    const int* ptok = wsi + WS_PTOK;
    int ntm = wsi[WS_NTILES];
    int nwork = ntm * (NF / BN);
    int tid  = threadIdx.x;
    int L    = tid & 63;
    int wv   = tid >> 6;                    // 8 waves
    int wr = wv & 3, wc = wv >> 2;          // wave grid: 4(M:32) x 2(N:64)
    unsigned l31 = (unsigned)(L & 31);
    unsigned hi16 = (unsigned)((L >> 5) * 16);
    unsigned arowb = ((unsigned)(wr*32) + l31) * 128u;
    unsigned arkey = (l31 & 7u) << 4;
    unsigned bcolb = ((unsigned)(wc*64) + l31) * 128u;
    unsigned brkey = ((l31 >> 1) & 7u) << 4;
    // B staging offsets: cols {2*(tid&63), +1}, k-octet wv
    unsigned bc2   = (unsigned)((tid & 63) * 2);
    unsigned boff0 = bc2*128u + (((unsigned)wv*16u) ^ (((bc2 >> 1) & 7u) << 4));
    int asw8 = ((L & 7) ^ (L >> 3)) * 8;    // pre-swizzled A source (f16 units)
    int srow = L >> 3;

    XCD_PART_LOOP(nwork){
        int widx = start_ + p_;
        int mt = widx % ntm;
        int ft = widx / ntm;
        int kexp = tk[mt];
        int row0 = tr[mt];
        int nrows = min(BM, seg[kexp+1] - row0);
        int f0 = ft * BN;
        __syncthreads();
        if (tid < BM){
            int r = row0 + tid;
            stok[tid] = (tid < nrows && r < pair_cap) ? ptok[r] : ptok[row0];
        }
        __syncthreads();
        const unsigned short* asrc[2];
        #pragma unroll
        for (int c = 0; c < 2; c++)
            asrc[c] = x16 + (size_t)stok[(wv*2 + c)*8 + srow] * ND;
        const float* bsrc = W1 + (size_t)kexp*ND*NF + f0 + (int)bc2;
        PIPE_LOOP(NF)
        // epilogue
        const float* b1k = b1 + (size_t)kexp*NF;
        #pragma unroll
        for (int n = 0; n < 2; n++){
            int f = f0 + wc*64 + n*32 + (int)l31;
            float bv = b1k[f];
            const f32x16& a = (n==0) ? acc0 : acc1;
            #pragma unroll
            for (int rg = 0; rg < 16; rg++){
                int row = wr*32 + (rg&3) + 8*(rg>>2) + 4*(L>>5);
                if (row < nrows && row0 + row < pair_cap){
                    float v = gelu_exact(a[rg] + bv);
                    hbuf[(size_t)(row0+row)*NF + f] = (unsigned short)(pkrtz(v, 0.f) & 0xffffu);
                }
            }
        }
    }
}

// ---------------- GEMM2 (split-K): y += coef*(h @ W2[k] + b2[k]) ----------------
__global__ __launch_bounds__(512, 4) void k_gemm2(
    const unsigned short* __restrict__ hbuf, const float* __restrict__ W2,
    const float* __restrict__ b2, const int* __restrict__ wsi,
    const float* __restrict__ wsf, float* __restrict__ out, int pair_cap)
{
    __shared__ char lds[65536];
    __shared__ int stok[BM];
    __shared__ float scoef[BM];
    const int* seg  = wsi + WS_SEG;
    const int* tk   = wsi + WS_TILEK;
    const int* tr   = wsi + WS_TILER;
    const int* ptok = wsi + WS_PTOK;
    const float* pcoef = wsf + WS_PCOEF;
    int ntm = wsi[WS_NTILES];
    int nwork = ntm * (ND / BN) * SPLITK2;
    int tid  = threadIdx.x;
    int L    = tid & 63;
    int wv   = tid >> 6;
    int wr = wv & 3, wc = wv >> 2;
    unsigned l31 = (unsigned)(L & 31);
    unsigned hi16 = (unsigned)((L >> 5) * 16);
    unsigned arowb = ((unsigned)(wr*32) + l31) * 128u;
    unsigned arkey = (l31 & 7u) << 4;
    unsigned bcolb = ((unsigned)(wc*64) + l31) * 128u;
    unsigned brkey = ((l31 >> 1) & 7u) << 4;
    unsigned bc2   = (unsigned)((tid & 63) * 2);
    unsigned boff0 = bc2*128u + (((unsigned)wv*16u) ^ (((bc2 >> 1) & 7u) << 4));
    int asw8 = ((L & 7) ^ (L >> 3)) * 8;
    int srow = L >> 3;

    XCD_PART_LOOP(nwork){
        int widx = start_ + p_;
        int mt = widx % ntm;
        int rest = widx / ntm;
        int dt = rest & 7;
        int spk = rest >> 3;
        int kexp = tk[mt];
        int row0 = tr[mt];
        int nrows = min(BM, seg[kexp+1] - row0);
        int d0 = dt * BN;
        __syncthreads();
        if (tid < BM){
            int r = row0 + tid;
            bool v = (tid < nrows && r < pair_cap);
            stok[tid]  = v ? ptok[r] : 0;
            scoef[tid] = v ? pcoef[r] : 0.f;
        }
        __syncthreads();
        const unsigned short* asrc[2];
        #pragma unroll
        for (int c = 0; c < 2; c++){
            int rg = row0 + (wv*2 + c)*8 + srow;
            if (rg >= pair_cap) rg = pair_cap - 1;
            asrc[c] = hbuf + (size_t)rg*NF + spk*(NF/SPLITK2);
        }
        const float* bsrc = W2 + (size_t)kexp*NF*ND + (size_t)spk*(NF/SPLITK2)*ND + d0 + (int)bc2;
        PIPE_LOOP(ND)
        // epilogue
        const float* b2k = b2 + (size_t)kexp*ND;
        #pragma unroll
        for (int n = 0; n < 2; n++){
            int d = d0 + wc*64 + n*32 + (int)l31;
            float bv = (spk == 0) ? b2k[d] : 0.f;
            const f32x16& a = (n==0) ? acc0 : acc1;
            #pragma unroll
            for (int rg = 0; rg < 16; rg++){
                int row = wr*32 + (rg&3) + 8*(rg>>2) + 4*(L>>5);
                if (row < nrows && row0 + row < pair_cap){
                    float c = scoef[row];
                    atomicAdd(&out[(size_t)stok[row]*ND + d], c * (a[rg] + bv));
                }
            }
        }
    }
}

extern "C" void kernel_launch(void* const* d_in, const int* in_sizes, int n_in,
                              void* d_out, int out_size, void* d_ws, size_t ws_size,
                              hipStream_t stream)
{
    const float* x   = (const float*)d_in[0];
    const float* pl  = (const float*)d_in[1];
    const float* Wt  = (const float*)d_in[2];
    const float* Wgt = (const float*)d_in[3];
    const float* Wel = (const float*)d_in[4];
    const float* W1  = (const float*)d_in[5];
    const float* b1  = (const float*)d_in[6];
    const float* W2  = (const float*)d_in[7];
    const float* b2  = (const float*)d_in[8];
    float* out = (float*)d_out;
    int* wsi   = (int*)d_ws;
    float* wsf = (float*)d_ws;
    unsigned short* x16  = (unsigned short*)((char*)d_ws + (size_t)WS_X16*4);
    unsigned short* hbuf = (unsigned short*)((char*)d_ws + (size_t)WS_H*4);

    long long avail = (long long)ws_size - (long long)WS_H*4;
    long long cap = avail / ((long long)NF*2);
    if (cap > (long long)NTOK*NK) cap = (long long)NTOK*NK;
    if (cap < 0) cap = 0;
    int pair_cap = (int)cap;

    hipMemsetAsync(d_out, 0, (size_t)out_size*sizeof(float), stream);
    hipMemsetAsync(d_ws, 0, 32, stream);
    k_xcast<<<1024, 256, 0, stream>>>(x, x16);
    k_gating<<<NTOK, 256, 0, stream>>>(x, pl, Wt, Wgt, Wel, out, wsf + WS_COEF, wsi + WS_CNT);
    if (pair_cap > 0){
        k_scan<<<NK, 256, 0, stream>>>(wsf + WS_COEF, wsi, wsf, pair_cap);
        k_tiles<<<1, 64, 0, stream>>>(wsi, out, pair_cap);
        k_gemm1<<<1024, 512, 0, stream>>>(x16, W1, b1, wsi, hbuf, pair_cap);
        k_gemm2<<<1024, 512, 0, stream>>>(hbuf, W2, b2, wsi, wsf, out, pair_cap);
    }
}

// Round 11
// 297.656 us; speedup vs baseline: 2.0141x; 1.8237x over previous
//
#include <hip/hip_runtime.h>
#include <cstdint>
#include <cstddef>

// Problem dims
#define NB 2
#define NTT 2048
#define ND 1024
#define NK 8
#define NF 4096
#define NTOK (NB*NTT)
#define LAMBDA_C 0.5f

// Output layout (float units)
#define Y_SZ   (NTOK*ND)
#define LG_OFF Y_SZ
#define SC_OFF (LG_OFF + NTOK*NK)
#define AD_OFF (SC_OFF + NK)

// Workspace layout (4-byte units)
#define WS_CNT    0
#define WS_SEG    8
#define WS_NTILES 17
#define WS_TILEK  32
#define WS_TILER  1056
#define WS_PTOK   4096
#define WS_PCOEF  36864
#define WS_COEF   69632
#define WS_X16    102400   // x as f16 (8MB)
#define WS_H      2199552  // f16 h buffer

#define BM 128
#define BN 128
#define BK 64
#define SPLITK2 4
#define KT 16

// LDS byte offsets: A dbuf 2x16KB, B dbuf 2x16KB
#define ASL0 0u
#define ASL1 16384u
#define BSL0 32768u
#define BSL1 49152u

typedef float  f32x2  __attribute__((ext_vector_type(2)));
typedef float  f32x4  __attribute__((ext_vector_type(4)));
typedef float  f32x16 __attribute__((ext_vector_type(16)));
typedef _Float16 f16x8 __attribute__((ext_vector_type(8)));
typedef unsigned int u32x4 __attribute__((ext_vector_type(4)));

__device__ __forceinline__ unsigned int pkrtz(float a, float b){
    auto h = __builtin_amdgcn_cvt_pkrtz(a, b);
    return __builtin_bit_cast(unsigned int, h);
}
__device__ __forceinline__ float gelu_exact(float v){
    return 0.5f * v * (1.0f + erff(v * 0.70710678118654752440f));
}

// ---------------- x -> f16 prepass ----------------
__global__ __launch_bounds__(256) void k_xcast(const float* __restrict__ x,
                                               unsigned short* __restrict__ x16)
{
    int i = (blockIdx.x*256 + threadIdx.x) * 16;
    const f32x4* src = (const f32x4*)(x + i);
    f32x4 v0 = src[0], v1 = src[1], v2 = src[2], v3 = src[3];
    u32x4 o0 = {pkrtz(v0[0],v0[1]), pkrtz(v0[2],v0[3]), pkrtz(v1[0],v1[1]), pkrtz(v1[2],v1[3])};
    u32x4 o1 = {pkrtz(v2[0],v2[1]), pkrtz(v2[2],v2[3]), pkrtz(v3[0],v3[1]), pkrtz(v3[2],v3[3])};
    *(u32x4*)(x16 + i)     = o0;
    *(u32x4*)(x16 + i + 8) = o1;
}

// ---------------- gating ----------------
__global__ __launch_bounds__(256) void k_gating(
    const float* __restrict__ x, const float* __restrict__ pl,
    const float* __restrict__ Wt, const float* __restrict__ Wgt,
    const float* __restrict__ Wel, float* __restrict__ out,
    float* __restrict__ coef, int* __restrict__ cnt)
{
    int t = blockIdx.x;
    const float* xt = x + (size_t)t * ND;
    float acc[NK] = {0,0,0,0,0,0,0,0};
    for (int d = threadIdx.x; d < ND; d += 256){
        float xv = xt[d];
        const float4* w = (const float4*)(Wt + (size_t)d * NK);
        float4 w0 = w[0], w1 = w[1];
        acc[0] += xv*w0.x; acc[1] += xv*w0.y; acc[2] += xv*w0.z; acc[3] += xv*w0.w;
        acc[4] += xv*w1.x; acc[5] += xv*w1.y; acc[6] += xv*w1.z; acc[7] += xv*w1.w;
    }
    __shared__ float red[4][NK];
    #pragma unroll
    for (int k = 0; k < NK; k++){
        float v = acc[k];
        #pragma unroll
        for (int off = 32; off; off >>= 1) v += __shfl_down(v, off);
        if ((threadIdx.x & 63) == 0) red[threadIdx.x >> 6][k] = v;
    }
    __syncthreads();
    if (threadIdx.x == 0){
        const float* p = pl + (size_t)t * NK;
        float pv[NK];
        #pragma unroll
        for (int j = 0; j < NK; j++) pv[j] = p[j];
        float lg[NK]; float mx = -1e30f;
        #pragma unroll
        for (int k = 0; k < NK; k++){
            float v = red[0][k] + red[1][k] + red[2][k] + red[3][k];
            #pragma unroll
            for (int j = 0; j < NK; j++) v += pv[j] * Wgt[j*NK + k];
            lg[k] = v; mx = fmaxf(mx, v);
            out[LG_OFF + (size_t)t*NK + k] = v;
        }
        float e[NK]; float s = 0.f;
        #pragma unroll
        for (int k = 0; k < NK; k++){ e[k] = expf(lg[k] - mx); s += e[k]; }
        float g[NK]; float gsum = 0.f;
        #pragma unroll
        for (int k = 0; k < NK; k++){
            float st = e[k] / s;
            float we = 1.f / (1.f + expf(-Wel[k]));
            bool m = st > LAMBDA_C * we;
            g[k] = m ? st : 0.f;
            gsum += g[k];
        }
        float inv = 1.f / (gsum + 1e-6f);
        #pragma unroll
        for (int k = 0; k < NK; k++){
            coef[(size_t)t*NK + k] = g[k] * inv;
            if (g[k] > 0.f) atomicAdd(&cnt[k], 1);
        }
    }
}

// ---------------- scan ----------------
__global__ __launch_bounds__(256) void k_scan(
    const float* __restrict__ coef, int* __restrict__ wsi,
    float* __restrict__ wsf, int pair_cap)
{
    int k = blockIdx.x;
    const int* cnt = wsi + WS_CNT;
    int base = 0;
    for (int j = 0; j < k; j++) base += cnt[j];
    int tid = threadIdx.x, lane = tid & 63, w = tid >> 6;
    __shared__ int wsum[4];
    __shared__ int sbase;
    if (tid == 0){
        sbase = base;
        wsi[WS_SEG + k] = base;
        if (k == NK-1) wsi[WS_SEG + NK] = base + cnt[k];
    }
    __syncthreads();
    int* ptok = wsi + WS_PTOK;
    float* pc = wsf + WS_PCOEF;
    for (int c0 = 0; c0 < NTOK; c0 += 256){
        int t = c0 + tid;
        float c = coef[(size_t)t*NK + k];
        bool m = c > 0.f;
        unsigned long long bal = __ballot(m);
        int pre = __popcll(bal & ((1ull << lane) - 1ull));
        if (lane == 0) wsum[w] = __popcll(bal);
        __syncthreads();
        int b = sbase;
        for (int j = 0; j < w; j++) b += wsum[j];
        if (m){
            int pos = b + pre;
            if (pos < pair_cap){ ptok[pos] = t; pc[pos] = c; }
        }
        __syncthreads();
        if (tid == 0) sbase += wsum[0] + wsum[1] + wsum[2] + wsum[3];
        __syncthreads();
    }
}

// ---------------- tiles + small outputs ----------------
__global__ void k_tiles(int* __restrict__ wsi, float* __restrict__ out, int pair_cap)
{
    if (threadIdx.x == 0 && blockIdx.x == 0){
        const int* cnt = wsi + WS_CNT;
        const int* seg = wsi + WS_SEG;
        int total = 0;
        for (int k = 0; k < NK; k++){ total += cnt[k]; out[SC_OFF + k] = (float)cnt[k]; }
        out[AD_OFF] = (float)total / (float)NTOK;
        int nt = 0;
        for (int k = 0; k < NK; k++){
            int e = min(seg[k+1], pair_cap);
            for (int r = seg[k]; r < e; r += BM){
                wsi[WS_TILEK + nt] = k; wsi[WS_TILER + nt] = r; nt++;
            }
        }
        wsi[WS_NTILES] = nt;
    }
}

// XCD-chunked bijective work partition
#define XCD_PART_LOOP(nwork)                                              \
    int q_ = (nwork) >> 3, rr_ = (nwork) & 7;                             \
    int xcd_ = blockIdx.x & 7;                                            \
    int slot_ = blockIdx.x >> 3;                                          \
    int nslot_ = gridDim.x >> 3;                                          \
    int cntw_ = q_ + (xcd_ < rr_ ? 1 : 0);                                \
    int start_ = xcd_ * q_ + (xcd_ < rr_ ? xcd_ : rr_);                   \
    for (int p_ = slot_; p_ < cntw_; p_ += nslot_)

// ---- shared GEMM building blocks (512 threads / 8 waves) ----
// A slot: row r (0..127) at r*128B; 16B granule g at (g*16)^((r&7)<<4);
//         filled by global_load_lds, 2 issues/wave, pre-swizzled source.
// B slot: col c (0..127) at c*128B; k-octet u (16B) at (u*16)^(((c>>1)&7)<<4).
// B staging: thread owns cols {2*(tid&63), +1}, k-octet u = wave id. Loads are
//            8 x f32x2, each 512B-contiguous across the 64 lanes of a wave.

#define LOADB(G_, tt_, LDW_)                                              \
  { const float* bn_ = bsrc + (size_t)((tt_)*BK + wv*8)*(LDW_);           \
    _Pragma("unroll")                                                     \
    for (int j9_ = 0; j9_ < 8; j9_++) G_[j9_] = *(const f32x2*)(bn_ + (size_t)j9_*(LDW_)); }

#define CVTWRB(G_, BO_)                                                   \
  { unsigned a0_ = pkrtz(G_[0][0], G_[1][0]);                             \
    unsigned a1_ = pkrtz(G_[2][0], G_[3][0]);                             \
    unsigned a2_ = pkrtz(G_[4][0], G_[5][0]);                             \
    unsigned a3_ = pkrtz(G_[6][0], G_[7][0]);                             \
    unsigned b0_ = pkrtz(G_[0][1], G_[1][1]);                             \
    unsigned b1_ = pkrtz(G_[2][1], G_[3][1]);                             \
    unsigned b2_ = pkrtz(G_[4][1], G_[5][1]);                             \
    unsigned b3_ = pkrtz(G_[6][1], G_[7][1]);                             \
    *(u32x4*)(&lds[(BO_) + boff0]) = (u32x4){a0_, a1_, a2_, a3_};         \
    *(u32x4*)(&lds[(BO_) + boff0 + 128u]) = (u32x4){b0_, b1_, b2_, b3_};  \
  }

#define GLL_A(AO_, tt_)                                                   \
  { _Pragma("unroll")                                                     \
    for (int c9_ = 0; c9_ < 2; c9_++){                                    \
        const unsigned short* g9_ = asrc[c9_] + (tt_)*BK + asw8;          \
        __builtin_amdgcn_global_load_lds(                                 \
            (const __attribute__((address_space(1))) void*)g9_,           \
            (__attribute__((address_space(3))) void*)(&lds[(AO_) + (unsigned)((wv*2 + c9_)*1024)]), \
            16, 0, 0);                                                    \
    } }

#define MFMA_PH(AO_, BO_)                                                 \
  { __builtin_amdgcn_s_setprio(1);                                        \
    _Pragma("unroll")                                                     \
    for (int s9_ = 0; s9_ < 4; s9_++){                                    \
        unsigned ko_ = (unsigned)(s9_*32) + hi16;                         \
        f16x8 a_  = *(const f16x8*)(&lds[(AO_) + arowb + (ko_ ^ arkey)]); \
        f16x8 b0_ = *(const f16x8*)(&lds[(BO_) + bcolb + (ko_ ^ brkey)]); \
        f16x8 b1_ = *(const f16x8*)(&lds[(BO_) + bcolb + 4096u + (ko_ ^ brkey)]); \
        acc0 = __builtin_amdgcn_mfma_f32_32x32x16_f16(a_, b0_, acc0, 0,0,0); \
        acc1 = __builtin_amdgcn_mfma_f32_32x32x16_f16(a_, b1_, acc1, 0,0,0); \
    }                                                                     \
    __builtin_amdgcn_s_setprio(0); }

// Depth-2 pipeline, per-thread vmem FIFO at iter entry:
//   [gen_t(8), GLL_t(2), gen_{t+1}(8)] = 18 outstanding.
//   vmcnt(10) drains exactly gen_t; vmcnt(8) drains exactly GLL_t;
//   gen_{t+1} stays in flight across the barrier.
#define PIPE_BODY(G_, AS_, BS_, AN_, tt_, LDW_)                           \
    asm volatile("s_waitcnt vmcnt(10)" ::: "memory");                     \
    CVTWRB(G_, BS_)                                                       \
    asm volatile("s_waitcnt vmcnt(8) lgkmcnt(0)" ::: "memory");           \
    __builtin_amdgcn_s_barrier();                                         \
    __builtin_amdgcn_sched_barrier(0);                                    \
    GLL_A(AN_, (tt_)+1)                                                   \
    if ((tt_) + 2 < KT){ LOADB(G_, (tt_)+2, LDW_) }                       \
    MFMA_PH(AS_, BS_)

#define PIPE_LOOP(LDW_)                                                   \
    f32x16 acc0 = {0}, acc1 = {0};                                        \
    f32x2 genA[8], genB[8];                                               \
    LOADB(genA, 0, LDW_)                                                  \
    GLL_A(ASL0, 0)                                                        \
    LOADB(genB, 1, LDW_)                                                  \
    for (int t = 0; t < KT-1; t++){                                       \
        if ((t & 1) == 0){ PIPE_BODY(genA, ASL0, BSL0, ASL1, t, LDW_) }   \
        else             { PIPE_BODY(genB, ASL1, BSL1, ASL0, t, LDW_) }   \
    }                                                                     \
    /* t = KT-1 (odd): outstanding = [genB(8), GLL_ASL1(2)] */            \
    asm volatile("s_waitcnt vmcnt(2)" ::: "memory");                      \
    CVTWRB(genB, BSL1)                                                    \
    asm volatile("s_waitcnt vmcnt(0) lgkmcnt(0)" ::: "memory");           \
    __builtin_amdgcn_s_barrier();                                         \
    __builtin_amdgcn_sched_barrier(0);                                    \
    MFMA_PH(ASL1, BSL1)

// ---------------- GEMM1: h = gelu(gather(x16) @ W1[k] + b1[k]) ----------------
__global__ __launch_bounds__(512, 2) void k_gemm1(
    const unsigned short* __restrict__ x16, const float* __restrict__ W1,
    const float* __restrict__ b1, const int* __restrict__ wsi,
    unsigned short* __restrict__ hbuf, int pair_cap)
{
    __shared__ char lds[65536];
    __shared__ int stok[BM];
    const int* seg  = wsi + WS_SEG;
    const int* tk   = wsi + WS_TILEK;
    const int* tr   = wsi + WS_TILER;
    const int* ptok = wsi + WS_PTOK;
    int ntm = wsi[WS_NTILES];
    int nwork = ntm * (NF / BN);
    int tid  = threadIdx.x;
    int L    = tid & 63;
    int wv   = tid >> 6;                    // 8 waves
    int wr = wv & 3, wc = wv >> 2;          // wave grid: 4(M:32) x 2(N:64)
    unsigned l31 = (unsigned)(L & 31);
    unsigned hi16 = (unsigned)((L >> 5) * 16);
    unsigned arowb = ((unsigned)(wr*32) + l31) * 128u;
    unsigned arkey = (l31 & 7u) << 4;
    unsigned bcolb = ((unsigned)(wc*64) + l31) * 128u;
    unsigned brkey = ((l31 >> 1) & 7u) << 4;
    // B staging offsets: cols {2*(tid&63), +1}, k-octet wv
    unsigned bc2   = (unsigned)((tid & 63) * 2);
    unsigned boff0 = bc2*128u + (((unsigned)wv*16u) ^ (((bc2 >> 1) & 7u) << 4));
    int asw8 = ((L & 7) ^ (L >> 3)) * 8;    // pre-swizzled A source (f16 units)
    int srow = L >> 3;

    XCD_PART_LOOP(nwork){
        int widx = start_ + p_;
        int mt = widx % ntm;
        int ft = widx / ntm;
        int kexp = tk[mt];
        int row0 = tr[mt];
        int nrows = min(BM, seg[kexp+1] - row0);
        int f0 = ft * BN;
        __syncthreads();
        if (tid < BM){
            int r = row0 + tid;
            stok[tid] = (tid < nrows && r < pair_cap) ? ptok[r] : ptok[row0];
        }
        __syncthreads();
        const unsigned short* asrc[2];
        #pragma unroll
        for (int c = 0; c < 2; c++)
            asrc[c] = x16 + (size_t)stok[(wv*2 + c)*8 + srow] * ND;
        const float* bsrc = W1 + (size_t)kexp*ND*NF + f0 + (int)bc2;
        PIPE_LOOP(NF)
        // epilogue
        const float* b1k = b1 + (size_t)kexp*NF;
        #pragma unroll
        for (int n = 0; n < 2; n++){
            int f = f0 + wc*64 + n*32 + (int)l31;
            float bv = b1k[f];
            const f32x16& a = (n==0) ? acc0 : acc1;
            #pragma unroll
            for (int rg = 0; rg < 16; rg++){
                int row = wr*32 + (rg&3) + 8*(rg>>2) + 4*(L>>5);
                if (row < nrows && row0 + row < pair_cap){
                    float v = gelu_exact(a[rg] + bv);
                    hbuf[(size_t)(row0+row)*NF + f] = (unsigned short)(pkrtz(v, 0.f) & 0xffffu);
                }
            }
        }
    }
}

// ---------------- GEMM2 (split-K): y += coef*(h @ W2[k] + b2[k]) ----------------
__global__ __launch_bounds__(512, 2) void k_gemm2(
    const unsigned short* __restrict__ hbuf, const float* __restrict__ W2,
    const float* __restrict__ b2, const int* __restrict__ wsi,
    const float* __restrict__ wsf, float* __restrict__ out, int pair_cap)
{
    __shared__ char lds[65536];
    __shared__ int stok[BM];
    __shared__ float scoef[BM];
    const int* seg  = wsi + WS_SEG;
    const int* tk   = wsi + WS_TILEK;
    const int* tr   = wsi + WS_TILER;
    const int* ptok = wsi + WS_PTOK;
    const float* pcoef = wsf + WS_PCOEF;
    int ntm = wsi[WS_NTILES];
    int nwork = ntm * (ND / BN) * SPLITK2;
    int tid  = threadIdx.x;
    int L    = tid & 63;
    int wv   = tid >> 6;
    int wr = wv & 3, wc = wv >> 2;
    unsigned l31 = (unsigned)(L & 31);
    unsigned hi16 = (unsigned)((L >> 5) * 16);
    unsigned arowb = ((unsigned)(wr*32) + l31) * 128u;
    unsigned arkey = (l31 & 7u) << 4;
    unsigned bcolb = ((unsigned)(wc*64) + l31) * 128u;
    unsigned brkey = ((l31 >> 1) & 7u) << 4;
    unsigned bc2   = (unsigned)((tid & 63) * 2);
    unsigned boff0 = bc2*128u + (((unsigned)wv*16u) ^ (((bc2 >> 1) & 7u) << 4));
    int asw8 = ((L & 7) ^ (L >> 3)) * 8;
    int srow = L >> 3;

    XCD_PART_LOOP(nwork){
        int widx = start_ + p_;
        int mt = widx % ntm;
        int rest = widx / ntm;
        int dt = rest & 7;
        int spk = rest >> 3;
        int kexp = tk[mt];
        int row0 = tr[mt];
        int nrows = min(BM, seg[kexp+1] - row0);
        int d0 = dt * BN;
        __syncthreads();
        if (tid < BM){
            int r = row0 + tid;
            bool v = (tid < nrows && r < pair_cap);
            stok[tid]  = v ? ptok[r] : 0;
            scoef[tid] = v ? pcoef[r] : 0.f;
        }
        __syncthreads();
        const unsigned short* asrc[2];
        #pragma unroll
        for (int c = 0; c < 2; c++){
            int rg = row0 + (wv*2 + c)*8 + srow;
            if (rg >= pair_cap) rg = pair_cap - 1;
            asrc[c] = hbuf + (size_t)rg*NF + spk*(NF/SPLITK2);
        }
        const float* bsrc = W2 + (size_t)kexp*NF*ND + (size_t)spk*(NF/SPLITK2)*ND + d0 + (int)bc2;
        PIPE_LOOP(ND)
        // epilogue
        const float* b2k = b2 + (size_t)kexp*ND;
        #pragma unroll
        for (int n = 0; n < 2; n++){
            int d = d0 + wc*64 + n*32 + (int)l31;
            float bv = (spk == 0) ? b2k[d] : 0.f;
            const f32x16& a = (n==0) ? acc0 : acc1;
            #pragma unroll
            for (int rg = 0; rg < 16; rg++){
                int row = wr*32 + (rg&3) + 8*(rg>>2) + 4*(L>>5);
                if (row < nrows && row0 + row < pair_cap){
                    float c = scoef[row];
                    atomicAdd(&out[(size_t)stok[row]*ND + d], c * (a[rg] + bv));
                }
            }
        }
    }
}

extern "C" void kernel_launch(void* const* d_in, const int* in_sizes, int n_in,
                              void* d_out, int out_size, void* d_ws, size_t ws_size,
                              hipStream_t stream)
{
    const float* x   = (const float*)d_in[0];
    const float* pl  = (const float*)d_in[1];
    const float* Wt  = (const float*)d_in[2];
    const float* Wgt = (const float*)d_in[3];
    const float* Wel = (const float*)d_in[4];
    const float* W1  = (const float*)d_in[5];
    const float* b1  = (const float*)d_in[6];
    const float* W2  = (const float*)d_in[7];
    const float* b2  = (const float*)d_in[8];
    float* out = (float*)d_out;
    int* wsi   = (int*)d_ws;
    float* wsf = (float*)d_ws;
    unsigned short* x16  = (unsigned short*)((char*)d_ws + (size_t)WS_X16*4);
    unsigned short* hbuf = (unsigned short*)((char*)d_ws + (size_t)WS_H*4);

    long long avail = (long long)ws_size - (long long)WS_H*4;
    long long cap = avail / ((long long)NF*2);
    if (cap > (long long)NTOK*NK) cap = (long long)NTOK*NK;
    if (cap < 0) cap = 0;
    int pair_cap = (int)cap;

    hipMemsetAsync(d_out, 0, (size_t)out_size*sizeof(float), stream);
    hipMemsetAsync(d_ws, 0, 32, stream);
    k_xcast<<<1024, 256, 0, stream>>>(x, x16);
    k_gating<<<NTOK, 256, 0, stream>>>(x, pl, Wt, Wgt, Wel, out, wsf + WS_COEF, wsi + WS_CNT);
    if (pair_cap > 0){
        k_scan<<<NK, 256, 0, stream>>>(wsf + WS_COEF, wsi, wsf, pair_cap);
        k_tiles<<<1, 64, 0, stream>>>(wsi, out, pair_cap);
        k_gemm1<<<1024, 512, 0, stream>>>(x16, W1, b1, wsi, hbuf, pair_cap);
        k_gemm2<<<1024, 512, 0, stream>>>(hbuf, W2, b2, wsi, wsf, out, pair_cap);
    }
}

// Round 12
// 273.000 us; speedup vs baseline: 2.1960x; 1.0903x over previous
//
#include <hip/hip_runtime.h>
#include <cstdint>
#include <cstddef>

// Problem dims
#define NB 2
#define NTT 2048
#define ND 1024
#define NK 8
#define NF 4096
#define NTOK (NB*NTT)
#define LAMBDA_C 0.5f

// Output layout (float units)
#define Y_SZ   (NTOK*ND)
#define LG_OFF Y_SZ
#define SC_OFF (LG_OFF + NTOK*NK)
#define AD_OFF (SC_OFF + NK)

// Workspace layout (4-byte units)
#define WS_CNT    0
#define WS_SEG    8
#define WS_NTILES 17
#define WS_TILEK  32
#define WS_TILER  1056
#define WS_PTOK   4096
#define WS_PCOEF  36864
#define WS_COEF   69632
#define WS_X16    102400   // x as f16 (8MB)
#define WS_H      2199552  // f16 h buffer

#define BM 128
#define BN 64
#define BK 64
#define SPLITK2 4
#define KT 16

typedef float  f32x2  __attribute__((ext_vector_type(2)));
typedef float  f32x4  __attribute__((ext_vector_type(4)));
typedef float  f32x16 __attribute__((ext_vector_type(16)));
typedef _Float16 f16x8 __attribute__((ext_vector_type(8)));
typedef unsigned int u32x4 __attribute__((ext_vector_type(4)));

// LDS: A slots 3x16KB @0, B slots 3x8KB @49152; total 73728B
__host__ __device__ constexpr unsigned ASLo(int i){ return (unsigned)(i*16384); }
__host__ __device__ constexpr unsigned BSLo(int i){ return (unsigned)(49152 + i*8192); }

__device__ __forceinline__ unsigned int pkrtz(float a, float b){
    auto h = __builtin_amdgcn_cvt_pkrtz(a, b);
    return __builtin_bit_cast(unsigned int, h);
}
__device__ __forceinline__ float gelu_exact(float v){
    return 0.5f * v * (1.0f + erff(v * 0.70710678118654752440f));
}

// ---------------- x -> f16 prepass ----------------
__global__ __launch_bounds__(256) void k_xcast(const float* __restrict__ x,
                                               unsigned short* __restrict__ x16)
{
    int i = (blockIdx.x*256 + threadIdx.x) * 16;
    const f32x4* src = (const f32x4*)(x + i);
    f32x4 v0 = src[0], v1 = src[1], v2 = src[2], v3 = src[3];
    u32x4 o0 = {pkrtz(v0[0],v0[1]), pkrtz(v0[2],v0[3]), pkrtz(v1[0],v1[1]), pkrtz(v1[2],v1[3])};
    u32x4 o1 = {pkrtz(v2[0],v2[1]), pkrtz(v2[2],v2[3]), pkrtz(v3[0],v3[1]), pkrtz(v3[2],v3[3])};
    *(u32x4*)(x16 + i)     = o0;
    *(u32x4*)(x16 + i + 8) = o1;
}

// ---------------- gating ----------------
__global__ __launch_bounds__(256) void k_gating(
    const float* __restrict__ x, const float* __restrict__ pl,
    const float* __restrict__ Wt, const float* __restrict__ Wgt,
    const float* __restrict__ Wel, float* __restrict__ out,
    float* __restrict__ coef, int* __restrict__ cnt)
{
    int t = blockIdx.x;
    const float* xt = x + (size_t)t * ND;
    float acc[NK] = {0,0,0,0,0,0,0,0};
    for (int d = threadIdx.x; d < ND; d += 256){
        float xv = xt[d];
        const float4* w = (const float4*)(Wt + (size_t)d * NK);
        float4 w0 = w[0], w1 = w[1];
        acc[0] += xv*w0.x; acc[1] += xv*w0.y; acc[2] += xv*w0.z; acc[3] += xv*w0.w;
        acc[4] += xv*w1.x; acc[5] += xv*w1.y; acc[6] += xv*w1.z; acc[7] += xv*w1.w;
    }
    __shared__ float red[4][NK];
    #pragma unroll
    for (int k = 0; k < NK; k++){
        float v = acc[k];
        #pragma unroll
        for (int off = 32; off; off >>= 1) v += __shfl_down(v, off);
        if ((threadIdx.x & 63) == 0) red[threadIdx.x >> 6][k] = v;
    }
    __syncthreads();
    if (threadIdx.x == 0){
        const float* p = pl + (size_t)t * NK;
        float pv[NK];
        #pragma unroll
        for (int j = 0; j < NK; j++) pv[j] = p[j];
        float lg[NK]; float mx = -1e30f;
        #pragma unroll
        for (int k = 0; k < NK; k++){
            float v = red[0][k] + red[1][k] + red[2][k] + red[3][k];
            #pragma unroll
            for (int j = 0; j < NK; j++) v += pv[j] * Wgt[j*NK + k];
            lg[k] = v; mx = fmaxf(mx, v);
            out[LG_OFF + (size_t)t*NK + k] = v;
        }
        float e[NK]; float s = 0.f;
        #pragma unroll
        for (int k = 0; k < NK; k++){ e[k] = expf(lg[k] - mx); s += e[k]; }
        float g[NK]; float gsum = 0.f;
        #pragma unroll
        for (int k = 0; k < NK; k++){
            float st = e[k] / s;
            float we = 1.f / (1.f + expf(-Wel[k]));
            bool m = st > LAMBDA_C * we;
            g[k] = m ? st : 0.f;
            gsum += g[k];
        }
        float inv = 1.f / (gsum + 1e-6f);
        #pragma unroll
        for (int k = 0; k < NK; k++){
            coef[(size_t)t*NK + k] = g[k] * inv;
            if (g[k] > 0.f) atomicAdd(&cnt[k], 1);
        }
    }
}

// ---------------- scan ----------------
__global__ __launch_bounds__(256) void k_scan(
    const float* __restrict__ coef, int* __restrict__ wsi,
    float* __restrict__ wsf, int pair_cap)
{
    int k = blockIdx.x;
    const int* cnt = wsi + WS_CNT;
    int base = 0;
    for (int j = 0; j < k; j++) base += cnt[j];
    int tid = threadIdx.x, lane = tid & 63, w = tid >> 6;
    __shared__ int wsum[4];
    __shared__ int sbase;
    if (tid == 0){
        sbase = base;
        wsi[WS_SEG + k] = base;
        if (k == NK-1) wsi[WS_SEG + NK] = base + cnt[k];
    }
    __syncthreads();
    int* ptok = wsi + WS_PTOK;
    float* pc = wsf + WS_PCOEF;
    for (int c0 = 0; c0 < NTOK; c0 += 256){
        int t = c0 + tid;
        float c = coef[(size_t)t*NK + k];
        bool m = c > 0.f;
        unsigned long long bal = __ballot(m);
        int pre = __popcll(bal & ((1ull << lane) - 1ull));
        if (lane == 0) wsum[w] = __popcll(bal);
        __syncthreads();
        int b = sbase;
        for (int j = 0; j < w; j++) b += wsum[j];
        if (m){
            int pos = b + pre;
            if (pos < pair_cap){ ptok[pos] = t; pc[pos] = c; }
        }
        __syncthreads();
        if (tid == 0) sbase += wsum[0] + wsum[1] + wsum[2] + wsum[3];
        __syncthreads();
    }
}

// ---------------- tiles + small outputs ----------------
__global__ void k_tiles(int* __restrict__ wsi, float* __restrict__ out, int pair_cap)
{
    if (threadIdx.x == 0 && blockIdx.x == 0){
        const int* cnt = wsi + WS_CNT;
        const int* seg = wsi + WS_SEG;
        int total = 0;
        for (int k = 0; k < NK; k++){ total += cnt[k]; out[SC_OFF + k] = (float)cnt[k]; }
        out[AD_OFF] = (float)total / (float)NTOK;
        int nt = 0;
        for (int k = 0; k < NK; k++){
            int e = min(seg[k+1], pair_cap);
            for (int r = seg[k]; r < e; r += BM){
                wsi[WS_TILEK + nt] = k; wsi[WS_TILER + nt] = r; nt++;
            }
        }
        wsi[WS_NTILES] = nt;
    }
}

// XCD-chunked bijective work partition
#define XCD_PART_LOOP(nwork)                                              \
    int q_ = (nwork) >> 3, rr_ = (nwork) & 7;                             \
    int xcd_ = blockIdx.x & 7;                                            \
    int slot_ = blockIdx.x >> 3;                                          \
    int nslot_ = gridDim.x >> 3;                                          \
    int cntw_ = q_ + (xcd_ < rr_ ? 1 : 0);                                \
    int start_ = xcd_ * q_ + (xcd_ < rr_ ? xcd_ : rr_);                   \
    for (int p_ = slot_; p_ < cntw_; p_ += nslot_)

// ---- building blocks (256 threads / 4 waves, wave tile 64x32) ----
// A slot (16KB): row r (0..127) at r*128B; 16B octet g at (g*16)^((r&7)<<4);
//   staged by global_load_lds (linear dest, pre-swizzled per-lane source).
// B slot (8KB): col c (0..63) at c*128B; k-octet u at (u*16)^(((c>>1)&7)<<4).
// B staging roles: ku = tid>>5 (k-octet), cpair = tid&31 (cols 2c,2c+1).

#define LOADB(G_, kk_, LDW_)                                              \
  { const float* bn_ = bsrc + (size_t)((kk_)*BK + ku*8)*(LDW_);           \
    _Pragma("unroll")                                                     \
    for (int j9_ = 0; j9_ < 8; j9_++) G_[j9_] = *(const f32x2*)(bn_ + (size_t)j9_*(LDW_)); }

#define CVTWRB(G_, BO_)                                                   \
  { _Pragma("unroll")                                                     \
    for (int cc_ = 0; cc_ < 2; cc_++){                                    \
        unsigned p0_ = pkrtz(G_[0][cc_], G_[1][cc_]);                     \
        unsigned p1_ = pkrtz(G_[2][cc_], G_[3][cc_]);                     \
        unsigned p2_ = pkrtz(G_[4][cc_], G_[5][cc_]);                     \
        unsigned p3_ = pkrtz(G_[6][cc_], G_[7][cc_]);                     \
        unsigned col_ = (unsigned)(cpair*2 + cc_);                        \
        unsigned off_ = (BO_) + col_*128u + (((unsigned)ku*16u) ^ (((unsigned)(cpair&7))<<4)); \
        *(u32x4*)(&lds[off_]) = (u32x4){p0_, p1_, p2_, p3_};              \
    } }

#define GLL_A(AO_, kk_)                                                   \
  { _Pragma("unroll")                                                     \
    for (int c9_ = 0; c9_ < 4; c9_++){                                    \
        const unsigned short* g9_ = asrc[c9_] + (kk_)*BK + asw8;          \
        __builtin_amdgcn_global_load_lds(                                 \
            (const __attribute__((address_space(1))) void*)g9_,           \
            (__attribute__((address_space(3))) void*)(&lds[(AO_) + (unsigned)(wv*4096 + c9_*1024)]), \
            16, 0, 0);                                                    \
    } }

#define MFMA_PH(AO_, BO_)                                                 \
  { __builtin_amdgcn_s_setprio(1);                                        \
    _Pragma("unroll")                                                     \
    for (int s9_ = 0; s9_ < 4; s9_++){                                    \
        unsigned ko_ = (unsigned)(s9_*32) + hi16;                         \
        f16x8 a0_ = *(const f16x8*)(&lds[(AO_) + arow0*128u + (ko_ ^ akey)]); \
        f16x8 a1_ = *(const f16x8*)(&lds[(AO_) + arow1*128u + (ko_ ^ akey)]); \
        f16x8 b_  = *(const f16x8*)(&lds[(BO_) + bcolb + (ko_ ^ bkey)]);  \
        acc0 = __builtin_amdgcn_mfma_f32_32x32x16_f16(a0_, b_, acc0, 0,0,0); \
        acc1 = __builtin_amdgcn_mfma_f32_32x32x16_f16(a1_, b_, acc1, 0,0,0); \
    }                                                                     \
    __builtin_amdgcn_s_setprio(0); }

// iter T (steady): top outstanding = [B(T+1)(8), GLL(T+1)(4), B(T+2)(8)]
#define PB_FULL(T_, GC_, GL_, LDW_)                                       \
    asm volatile("s_waitcnt vmcnt(8)" ::: "memory");                      \
    CVTWRB(GC_, BSLo(((T_)+1)%3))                                         \
    asm volatile("s_waitcnt lgkmcnt(0)" ::: "memory");                    \
    __builtin_amdgcn_s_barrier();                                         \
    __builtin_amdgcn_sched_barrier(0);                                    \
    GLL_A(ASLo(((T_)+2)%3), (T_)+2)                                       \
    LOADB(GL_, (T_)+3, LDW_)                                              \
    MFMA_PH(ASLo((T_)%3), BSLo((T_)%3))

#define PIPE_LOOP(LDW_)                                                   \
    f32x16 acc0 = {0}, acc1 = {0};                                        \
    f32x2 g0[8], g1[8], g2[8];                                            \
    LOADB(g0, 0, LDW_)                                                    \
    GLL_A(ASLo(0), 0)                                                     \
    asm volatile("s_waitcnt vmcnt(4)" ::: "memory");                      \
    CVTWRB(g0, BSLo(0))                                                   \
    LOADB(g1, 1, LDW_)                                                    \
    GLL_A(ASLo(1), 1)                                                     \
    LOADB(g2, 2, LDW_)                                                    \
    asm volatile("s_waitcnt vmcnt(20) lgkmcnt(0)" ::: "memory");          \
    __builtin_amdgcn_s_barrier();                                         \
    __builtin_amdgcn_sched_barrier(0);                                    \
    PB_FULL(0,  g1, g0, LDW_)  PB_FULL(1,  g2, g1, LDW_)                  \
    PB_FULL(2,  g0, g2, LDW_)  PB_FULL(3,  g1, g0, LDW_)                  \
    PB_FULL(4,  g2, g1, LDW_)  PB_FULL(5,  g0, g2, LDW_)                  \
    PB_FULL(6,  g1, g0, LDW_)  PB_FULL(7,  g2, g1, LDW_)                  \
    PB_FULL(8,  g0, g2, LDW_)  PB_FULL(9,  g1, g0, LDW_)                  \
    PB_FULL(10, g2, g1, LDW_)  PB_FULL(11, g0, g2, LDW_)                  \
    PB_FULL(12, g1, g0, LDW_)                                             \
    /* T=13: no LOADB(16) */                                              \
    asm volatile("s_waitcnt vmcnt(8)" ::: "memory");                      \
    CVTWRB(g2, BSLo(2))                                                   \
    asm volatile("s_waitcnt lgkmcnt(0)" ::: "memory");                    \
    __builtin_amdgcn_s_barrier();                                         \
    __builtin_amdgcn_sched_barrier(0);                                    \
    GLL_A(ASLo(0), 15)                                                    \
    MFMA_PH(ASLo(1), BSLo(1))                                             \
    /* T=14: drain all, stage last B */                                   \
    asm volatile("s_waitcnt vmcnt(0)" ::: "memory");                      \
    CVTWRB(g0, BSLo(0))                                                   \
    asm volatile("s_waitcnt lgkmcnt(0)" ::: "memory");                    \
    __builtin_amdgcn_s_barrier();                                         \
    __builtin_amdgcn_sched_barrier(0);                                    \
    MFMA_PH(ASLo(2), BSLo(2))                                             \
    /* T=15 */                                                            \
    MFMA_PH(ASLo(0), BSLo(0))

// ---------------- GEMM1: h = gelu(gather(x16) @ W1[k] + b1[k]) ----------------
__global__ __launch_bounds__(256, 2) void k_gemm1(
    const unsigned short* __restrict__ x16, const float* __restrict__ W1,
    const float* __restrict__ b1, const int* __restrict__ wsi,
    unsigned short* __restrict__ hbuf, int pair_cap)
{
    __shared__ char lds[73728];
    __shared__ int stok[BM];
    const int* seg  = wsi + WS_SEG;
    const int* tk   = wsi + WS_TILEK;
    const int* tr   = wsi + WS_TILER;
    const int* ptok = wsi + WS_PTOK;
    int ntm = wsi[WS_NTILES];
    int nwork = ntm * (NF / BN);
    int tid  = threadIdx.x;
    int L    = tid & 63;
    int wv   = tid >> 6;                 // 4 waves
    int wr = wv >> 1, wc = wv & 1;       // wave tile 64(M) x 32(N)
    unsigned l31 = (unsigned)(L & 31);
    unsigned hi16 = (unsigned)((L >> 5) * 16);
    unsigned arow0 = (unsigned)(wr*64) + l31;
    unsigned arow1 = arow0 + 32u;
    unsigned akey  = (l31 & 7u) << 4;
    unsigned bcolb = ((unsigned)(wc*32) + l31) * 128u;
    unsigned bkey  = (((((unsigned)(wc*32) + l31) >> 1) & 7u) << 4);
    int ku = tid >> 5, cpair = tid & 31; // B staging roles
    int asw8 = ((L & 7) ^ ((L >> 3) & 7)) * 8;
    int srow = L >> 3;

    XCD_PART_LOOP(nwork){
        int widx = start_ + p_;
        int mt = widx % ntm;
        int ft = widx / ntm;
        int kexp = tk[mt];
        int row0 = tr[mt];
        int nrows = min(BM, seg[kexp+1] - row0);
        int f0 = ft * BN;
        __syncthreads();
        if (tid < BM){
            int r = row0 + tid;
            stok[tid] = (tid < nrows && r < pair_cap) ? ptok[r] : ptok[row0];
        }
        __syncthreads();
        const unsigned short* asrc[4];
        #pragma unroll
        for (int c = 0; c < 4; c++)
            asrc[c] = x16 + (size_t)stok[wv*32 + c*8 + srow] * ND;
        const float* bsrc = W1 + (size_t)kexp*ND*NF + f0 + cpair*2;
        PIPE_LOOP(NF)
        // epilogue
        const float* b1k = b1 + (size_t)kexp*NF;
        int f = f0 + wc*32 + (int)l31;
        float bv = b1k[f];
        #pragma unroll
        for (int m = 0; m < 2; m++){
            const f32x16& a = (m==0) ? acc0 : acc1;
            #pragma unroll
            for (int rg = 0; rg < 16; rg++){
                int row = wr*64 + m*32 + (rg&3) + 8*(rg>>2) + 4*(L>>5);
                if (row < nrows && row0 + row < pair_cap){
                    float v = gelu_exact(a[rg] + bv);
                    hbuf[(size_t)(row0+row)*NF + f] = (unsigned short)(pkrtz(v, 0.f) & 0xffffu);
                }
            }
        }
    }
}

// ---------------- GEMM2 (split-K): y += coef*(h @ W2[k] + b2[k]) ----------------
__global__ __launch_bounds__(256, 2) void k_gemm2(
    const unsigned short* __restrict__ hbuf, const float* __restrict__ W2,
    const float* __restrict__ b2, const int* __restrict__ wsi,
    const float* __restrict__ wsf, float* __restrict__ out, int pair_cap)
{
    __shared__ char lds[73728];
    __shared__ int stok[BM];
    __shared__ float scoef[BM];
    const int* seg  = wsi + WS_SEG;
    const int* tk   = wsi + WS_TILEK;
    const int* tr   = wsi + WS_TILER;
    const int* ptok = wsi + WS_PTOK;
    const float* pcoef = wsf + WS_PCOEF;
    int ntm = wsi[WS_NTILES];
    int nwork = ntm * (ND / BN) * SPLITK2;   // mt fastest, dt(16), spk(4)
    int tid  = threadIdx.x;
    int L    = tid & 63;
    int wv   = tid >> 6;
    int wr = wv >> 1, wc = wv & 1;
    unsigned l31 = (unsigned)(L & 31);
    unsigned hi16 = (unsigned)((L >> 5) * 16);
    unsigned arow0 = (unsigned)(wr*64) + l31;
    unsigned arow1 = arow0 + 32u;
    unsigned akey  = (l31 & 7u) << 4;
    unsigned bcolb = ((unsigned)(wc*32) + l31) * 128u;
    unsigned bkey  = (((((unsigned)(wc*32) + l31) >> 1) & 7u) << 4);
    int ku = tid >> 5, cpair = tid & 31;
    int asw8 = ((L & 7) ^ ((L >> 3) & 7)) * 8;
    int srow = L >> 3;

    XCD_PART_LOOP(nwork){
        int widx = start_ + p_;
        int mt = widx % ntm;
        int rest = widx / ntm;
        int dt = rest & 15;
        int spk = rest >> 4;
        int kexp = tk[mt];
        int row0 = tr[mt];
        int nrows = min(BM, seg[kexp+1] - row0);
        int d0 = dt * BN;
        __syncthreads();
        if (tid < BM){
            int r = row0 + tid;
            bool v = (tid < nrows && r < pair_cap);
            stok[tid]  = v ? ptok[r] : 0;
            scoef[tid] = v ? pcoef[r] : 0.f;
        }
        __syncthreads();
        const unsigned short* asrc[4];
        #pragma unroll
        for (int c = 0; c < 4; c++){
            int rg = row0 + wv*32 + c*8 + srow;
            if (rg >= pair_cap) rg = pair_cap - 1;
            asrc[c] = hbuf + (size_t)rg*NF + spk*(NF/SPLITK2);
        }
        const float* bsrc = W2 + (size_t)kexp*NF*ND + (size_t)spk*(NF/SPLITK2)*ND + d0 + cpair*2;
        PIPE_LOOP(ND)
        // epilogue
        const float* b2k = b2 + (size_t)kexp*ND;
        int d = d0 + wc*32 + (int)l31;
        float bv = (spk == 0) ? b2k[d] : 0.f;
        #pragma unroll
        for (int m = 0; m < 2; m++){
            const f32x16& a = (m==0) ? acc0 : acc1;
            #pragma unroll
            for (int rg = 0; rg < 16; rg++){
                int row = wr*64 + m*32 + (rg&3) + 8*(rg>>2) + 4*(L>>5);
                if (row < nrows && row0 + row < pair_cap){
                    float c = scoef[row];
                    atomicAdd(&out[(size_t)stok[row]*ND + d], c * (a[rg] + bv));
                }
            }
        }
    }
}

extern "C" void kernel_launch(void* const* d_in, const int* in_sizes, int n_in,
                              void* d_out, int out_size, void* d_ws, size_t ws_size,
                              hipStream_t stream)
{
    const float* x   = (const float*)d_in[0];
    const float* pl  = (const float*)d_in[1];
    const float* Wt  = (const float*)d_in[2];
    const float* Wgt = (const float*)d_in[3];
    const float* Wel = (const float*)d_in[4];
    const float* W1  = (const float*)d_in[5];
    const float* b1  = (const float*)d_in[6];
    const float* W2  = (const float*)d_in[7];
    const float* b2  = (const float*)d_in[8];
    float* out = (float*)d_out;
    int* wsi   = (int*)d_ws;
    float* wsf = (float*)d_ws;
    unsigned short* x16  = (unsigned short*)((char*)d_ws + (size_t)WS_X16*4);
    unsigned short* hbuf = (unsigned short*)((char*)d_ws + (size_t)WS_H*4);

    long long avail = (long long)ws_size - (long long)WS_H*4;
    long long cap = avail / ((long long)NF*2);
    if (cap > (long long)NTOK*NK) cap = (long long)NTOK*NK;
    if (cap < 0) cap = 0;
    int pair_cap = (int)cap;

    hipMemsetAsync(d_out, 0, (size_t)out_size*sizeof(float), stream);
    hipMemsetAsync(d_ws, 0, 32, stream);
    k_xcast<<<1024, 256, 0, stream>>>(x, x16);
    k_gating<<<NTOK, 256, 0, stream>>>(x, pl, Wt, Wgt, Wel, out, wsf + WS_COEF, wsi + WS_CNT);
    if (pair_cap > 0){
        k_scan<<<NK, 256, 0, stream>>>(wsf + WS_COEF, wsi, wsf, pair_cap);
        k_tiles<<<1, 64, 0, stream>>>(wsi, out, pair_cap);
        k_gemm1<<<2048, 256, 0, stream>>>(x16, W1, b1, wsi, hbuf, pair_cap);
        k_gemm2<<<2048, 256, 0, stream>>>(hbuf, W2, b2, wsi, wsf, out, pair_cap);
    }
}

// Round 13
// 244.355 us; speedup vs baseline: 2.4535x; 1.1172x over previous
//
#include <hip/hip_runtime.h>
#include <cstdint>
#include <cstddef>

// Problem dims
#define NB 2
#define NTT 2048
#define ND 1024
#define NK 8
#define NF 4096
#define NTOK (NB*NTT)        // 4096 tokens
#define LAMBDA_C 0.5f

// Output layout (float units)
#define Y_SZ   (NTOK*ND)
#define LG_OFF Y_SZ
#define SC_OFF (LG_OFF + NTOK*NK)
#define AD_OFF (SC_OFF + NK)

// Workspace layout (4-byte units)
#define WS_CNT    0
#define WS_SEG    8
#define WS_NTILES 17
#define WS_TILEK  32
#define WS_TILER  1056
#define WS_PTOK   4096
#define WS_PCOEF  36864
#define WS_COEF   69632
#define WS_X16    102400   // x as f16 (8MB)
#define WS_H      2199552  // f16 h buffer

#define BM 128
#define BN 64
#define BK 64
#define SPLITK2 4
#define KT 16              // K-steps per item (both gemms)

// LDS offsets (bytes): A slots 2x16KB, B slots 2x8KB
#define AOFF0 0u
#define AOFF1 16384u
#define BOFF0 32768u
#define BOFF1 40960u

typedef float  f32x4 __attribute__((ext_vector_type(4)));
typedef _Float16 f16x8 __attribute__((ext_vector_type(8)));
typedef unsigned int u32x2 __attribute__((ext_vector_type(2)));
typedef unsigned int u32x4 __attribute__((ext_vector_type(4)));

__device__ __forceinline__ unsigned int pkrtz(float a, float b){
    auto h = __builtin_amdgcn_cvt_pkrtz(a, b);
    return __builtin_bit_cast(unsigned int, h);
}
__device__ __forceinline__ float gelu_exact(float v){
    return 0.5f * v * (1.0f + erff(v * 0.70710678118654752440f));
}

// ---------------- x -> f16 prepass ----------------
__global__ __launch_bounds__(256) void k_xcast(const float* __restrict__ x,
                                               unsigned short* __restrict__ x16)
{
    int i = (blockIdx.x*256 + threadIdx.x) * 16;
    const f32x4* src = (const f32x4*)(x + i);
    f32x4 v0 = src[0], v1 = src[1], v2 = src[2], v3 = src[3];
    u32x4 o0 = {pkrtz(v0[0],v0[1]), pkrtz(v0[2],v0[3]), pkrtz(v1[0],v1[1]), pkrtz(v1[2],v1[3])};
    u32x4 o1 = {pkrtz(v2[0],v2[1]), pkrtz(v2[2],v2[3]), pkrtz(v3[0],v3[1]), pkrtz(v3[2],v3[3])};
    *(u32x4*)(x16 + i)     = o0;
    *(u32x4*)(x16 + i + 8) = o1;
}

// ---------------- gating ----------------
__global__ __launch_bounds__(256) void k_gating(
    const float* __restrict__ x, const float* __restrict__ pl,
    const float* __restrict__ Wt, const float* __restrict__ Wgt,
    const float* __restrict__ Wel, float* __restrict__ out,
    float* __restrict__ coef, int* __restrict__ cnt)
{
    int t = blockIdx.x;
    const float* xt = x + (size_t)t * ND;
    float acc[NK] = {0,0,0,0,0,0,0,0};
    for (int d = threadIdx.x; d < ND; d += 256){
        float xv = xt[d];
        const float4* w = (const float4*)(Wt + (size_t)d * NK);
        float4 w0 = w[0], w1 = w[1];
        acc[0] += xv*w0.x; acc[1] += xv*w0.y; acc[2] += xv*w0.z; acc[3] += xv*w0.w;
        acc[4] += xv*w1.x; acc[5] += xv*w1.y; acc[6] += xv*w1.z; acc[7] += xv*w1.w;
    }
    __shared__ float red[4][NK];
    #pragma unroll
    for (int k = 0; k < NK; k++){
        float v = acc[k];
        #pragma unroll
        for (int off = 32; off; off >>= 1) v += __shfl_down(v, off);
        if ((threadIdx.x & 63) == 0) red[threadIdx.x >> 6][k] = v;
    }
    __syncthreads();
    if (threadIdx.x == 0){
        const float* p = pl + (size_t)t * NK;
        float pv[NK];
        #pragma unroll
        for (int j = 0; j < NK; j++) pv[j] = p[j];
        float lg[NK]; float mx = -1e30f;
        #pragma unroll
        for (int k = 0; k < NK; k++){
            float v = red[0][k] + red[1][k] + red[2][k] + red[3][k];
            #pragma unroll
            for (int j = 0; j < NK; j++) v += pv[j] * Wgt[j*NK + k];
            lg[k] = v; mx = fmaxf(mx, v);
            out[LG_OFF + (size_t)t*NK + k] = v;
        }
        float e[NK]; float s = 0.f;
        #pragma unroll
        for (int k = 0; k < NK; k++){ e[k] = expf(lg[k] - mx); s += e[k]; }
        float g[NK]; float gsum = 0.f;
        #pragma unroll
        for (int k = 0; k < NK; k++){
            float st = e[k] / s;
            float we = 1.f / (1.f + expf(-Wel[k]));
            bool m = st > LAMBDA_C * we;
            g[k] = m ? st : 0.f;
            gsum += g[k];
        }
        float inv = 1.f / (gsum + 1e-6f);
        #pragma unroll
        for (int k = 0; k < NK; k++){
            coef[(size_t)t*NK + k] = g[k] * inv;
            if (g[k] > 0.f) atomicAdd(&cnt[k], 1);
        }
    }
}

// ---------------- scan: per-expert compaction (8 blocks) ----------------
__global__ __launch_bounds__(256) void k_scan(
    const float* __restrict__ coef, int* __restrict__ wsi,
    float* __restrict__ wsf, int pair_cap)
{
    int k = blockIdx.x;
    const int* cnt = wsi + WS_CNT;
    int base = 0;
    for (int j = 0; j < k; j++) base += cnt[j];
    int tid = threadIdx.x, lane = tid & 63, w = tid >> 6;
    __shared__ int wsum[4];
    __shared__ int sbase;
    if (tid == 0){
        sbase = base;
        wsi[WS_SEG + k] = base;
        if (k == NK-1) wsi[WS_SEG + NK] = base + cnt[k];
    }
    __syncthreads();
    int* ptok = wsi + WS_PTOK;
    float* pc = wsf + WS_PCOEF;
    for (int c0 = 0; c0 < NTOK; c0 += 256){
        int t = c0 + tid;
        float c = coef[(size_t)t*NK + k];
        bool m = c > 0.f;
        unsigned long long bal = __ballot(m);
        int pre = __popcll(bal & ((1ull << lane) - 1ull));
        if (lane == 0) wsum[w] = __popcll(bal);
        __syncthreads();
        int b = sbase;
        for (int j = 0; j < w; j++) b += wsum[j];
        if (m){
            int pos = b + pre;
            if (pos < pair_cap){ ptok[pos] = t; pc[pos] = c; }
        }
        __syncthreads();
        if (tid == 0) sbase += wsum[0] + wsum[1] + wsum[2] + wsum[3];
        __syncthreads();
    }
}

// ---------------- tiles + small outputs ----------------
__global__ void k_tiles(int* __restrict__ wsi, float* __restrict__ out, int pair_cap)
{
    if (threadIdx.x == 0 && blockIdx.x == 0){
        const int* cnt = wsi + WS_CNT;
        const int* seg = wsi + WS_SEG;
        int total = 0;
        for (int k = 0; k < NK; k++){ total += cnt[k]; out[SC_OFF + k] = (float)cnt[k]; }
        out[AD_OFF] = (float)total / (float)NTOK;
        int nt = 0;
        for (int k = 0; k < NK; k++){
            int e = min(seg[k+1], pair_cap);
            for (int r = seg[k]; r < e; r += BM){
                wsi[WS_TILEK + nt] = k; wsi[WS_TILER + nt] = r; nt++;
            }
        }
        wsi[WS_NTILES] = nt;
    }
}

// XCD-chunked bijective work partition
#define XCD_PART_LOOP(nwork)                                              \
    int q_ = (nwork) >> 3, rr_ = (nwork) & 7;                             \
    int xcd_ = blockIdx.x & 7;                                            \
    int slot_ = blockIdx.x >> 3;                                          \
    int nslot_ = gridDim.x >> 3;                                          \
    int cntw_ = q_ + (xcd_ < rr_ ? 1 : 0);                                \
    int start_ = xcd_ * q_ + (xcd_ < rr_ ? xcd_ : rr_);                   \
    for (int p_ = slot_; p_ < cntw_; p_ += nslot_)

// ---- staging / MFMA building blocks ----
// A LDS slot: 128 rows x 64 f16; row r at r*128B; seg s (16B) at (s^(r&7))*16
// B LDS slot: 64 cols x 64 f16 k-major; col c at c*128B; k-quad kq (8B) at (kq*8)^((c&7)<<4)

#define LOAD_A(dst_, tt_)                                                 \
    { const unsigned short* an_ = asrc + (tt_)*BK;                        \
      _Pragma("unroll")                                                   \
      for (int j_ = 0; j_ < 4; j_++) dst_[j_] = *(const u32x4*)(an_ + j_*8); }

#define LOAD_B(dst_, tt_, LDW_)                                           \
    { const float* bn_ = bsrc + (size_t)((tt_)*BK + bkq*4)*LDW_;          \
      _Pragma("unroll")                                                   \
      for (int r_ = 0; r_ < 4; r_++) dst_[r_] = *(const f32x4*)(bn_ + (size_t)r_*LDW_); }

#define STAGE_A(src_, AO_)                                                \
    { _Pragma("unroll")                                                   \
      for (int j_ = 0; j_ < 4; j_++){                                     \
          unsigned off_ = (AO_) + (unsigned)arow*128u +                   \
              ((((unsigned)(ahalf*4 + j_)) ^ (unsigned)(arow & 7)) << 4); \
          *(u32x4*)(&lds[off_]) = src_[j_];                               \
      } }

#define STAGE_B(src_, BO_)                                                \
    { unsigned wA_[4], wB_[4];                                            \
      _Pragma("unroll")                                                   \
      for (int r_ = 0; r_ < 4; r_++){                                     \
          wA_[r_] = pkrtz(src_[r_][0], src_[r_][1]);                      \
          wB_[r_] = pkrtz(src_[r_][2], src_[r_][3]);                      \
      }                                                                   \
      _Pragma("unroll")                                                   \
      for (int j_ = 0; j_ < 4; j_++){                                     \
          unsigned s0_ = (j_ < 2) ? wA_[1] : wB_[1];                      \
          unsigned s1_ = (j_ < 2) ? wA_[0] : wB_[0];                      \
          unsigned s2_ = (j_ < 2) ? wA_[3] : wB_[3];                      \
          unsigned s3_ = (j_ < 2) ? wA_[2] : wB_[2];                      \
          unsigned sel_ = (j_ & 1) ? 0x07060302u : 0x05040100u;           \
          unsigned o0_ = __builtin_amdgcn_perm(s0_, s1_, sel_);           \
          unsigned o1_ = __builtin_amdgcn_perm(s2_, s3_, sel_);           \
          unsigned col_ = (unsigned)(bcc*4 + j_);                         \
          unsigned off_ = (BO_) + col_*128u +                             \
              (((unsigned)(bkq*8)) ^ ((col_ & 7u) << 4));                 \
          *(u32x2*)(&lds[off_]) = (u32x2){o0_, o1_};                      \
      } }

#define MFMA_RD(AO_, BO_)                                                 \
    { __builtin_amdgcn_s_setprio(1);                                      \
      _Pragma("unroll")                                                   \
      for (int kk_ = 0; kk_ < 2; kk_++){                                  \
          unsigned sb_ = ((unsigned)(kk_*64 + q*16)) ^ swzL;              \
          f16x8 af_[4], bf_[2];                                           \
          _Pragma("unroll")                                               \
          for (int m_ = 0; m_ < 4; m_++)                                  \
              af_[m_] = *(const f16x8*)(&lds[(AO_) + (unsigned)(wr*64 + m_*16 + l15)*128u + sb_]); \
          _Pragma("unroll")                                               \
          for (int n_ = 0; n_ < 2; n_++)                                  \
              bf_[n_] = *(const f16x8*)(&lds[(BO_) + (unsigned)(wc*32 + n_*16 + l15)*128u + sb_]); \
          _Pragma("unroll")                                               \
          for (int m_ = 0; m_ < 4; m_++)                                  \
          _Pragma("unroll")                                               \
          for (int n_ = 0; n_ < 2; n_++)                                  \
              acc[m_][n_] = __builtin_amdgcn_mfma_f32_16x16x32_f16(af_[m_], bf_[n_], acc[m_][n_], 0, 0, 0); \
      }                                                                   \
      __builtin_amdgcn_s_setprio(0); }

// Raw barrier: only LDS-write visibility needed. NO vmcnt here — global-load
// completion is enforced by the compiler's auto-counted waits at the point
// STAGE consumes the gen registers (2 iterations after issue).
#define STEP_SYNC()                                                       \
    asm volatile("s_waitcnt lgkmcnt(0)" ::: "memory");                    \
    __builtin_amdgcn_s_barrier();                                         \
    __builtin_amdgcn_sched_barrier(0);

// ---------------- GEMM1: h = gelu(gather(x16) @ W1[k] + b1[k]) ----------------
__global__ __launch_bounds__(256, 3) void k_gemm1(
    const unsigned short* __restrict__ x16, const float* __restrict__ W1,
    const float* __restrict__ b1, const int* __restrict__ wsi,
    unsigned short* __restrict__ hbuf, int pair_cap)
{
    __shared__ char lds[49152];
    __shared__ int stok[BM];
    const int* seg  = wsi + WS_SEG;
    const int* tk   = wsi + WS_TILEK;
    const int* tr   = wsi + WS_TILER;
    const int* ptok = wsi + WS_PTOK;
    int ntm = wsi[WS_NTILES];
    int nwork = ntm * (NF / BN);
    int tid  = threadIdx.x;
    int lane = tid & 63;
    int w    = tid >> 6;
    int wr = w >> 1, wc = w & 1;
    int l15 = lane & 15, q = lane >> 4;
    unsigned swzL = (unsigned)((l15 & 7) << 4);
    int arow = tid >> 1, ahalf = tid & 1;
    int bkq = tid >> 4, bcc = tid & 15;

    XCD_PART_LOOP(nwork){
        int widx = start_ + p_;
        int mt = widx % ntm;
        int ft = widx / ntm;
        int kexp = tk[mt];
        int row0 = tr[mt];
        int nrows = min(BM, seg[kexp+1] - row0);
        int f0 = ft * BN;
        __syncthreads();
        if (tid < BM){
            int r = row0 + tid;
            stok[tid] = (tid < nrows && r < pair_cap) ? ptok[r] : ptok[row0];
        }
        __syncthreads();
        const unsigned short* asrc = x16 + (size_t)stok[arow]*ND + ahalf*32;
        const float* bsrc = W1 + (size_t)kexp*ND*NF + f0 + bcc*4;
        u32x4 ga0[4], ga1[4]; f32x4 gb0[4], gb1[4];
        LOAD_A(ga0, 0) LOAD_B(gb0, 0, NF)
        LOAD_A(ga1, 1) LOAD_B(gb1, 1, NF)
        f32x4 acc[4][2] = {};
        for (int t = 0; t < KT; t += 2){
            // even step: consume gen0 -> slot0
            STAGE_A(ga0, AOFF0) STAGE_B(gb0, BOFF0)
            if (t + 2 < KT){ LOAD_A(ga0, t+2) LOAD_B(gb0, t+2, NF) }
            STEP_SYNC()
            MFMA_RD(AOFF0, BOFF0)
            // odd step: consume gen1 -> slot1
            STAGE_A(ga1, AOFF1) STAGE_B(gb1, BOFF1)
            if (t + 3 < KT){ LOAD_A(ga1, t+3) LOAD_B(gb1, t+3, NF) }
            STEP_SYNC()
            MFMA_RD(AOFF1, BOFF1)
        }
        const float* b1k = b1 + (size_t)kexp*NF;
        #pragma unroll
        for (int n = 0; n < 2; n++){
            int f = f0 + wc*32 + n*16 + l15;
            float bv = b1k[f];
            #pragma unroll
            for (int m = 0; m < 4; m++){
                int rl = wr*64 + m*16 + q*4;
                #pragma unroll
                for (int i = 0; i < 4; i++){
                    int r = rl + i;
                    if (r < nrows && row0 + r < pair_cap){
                        float v = gelu_exact(acc[m][n][i] + bv);
                        hbuf[(size_t)(row0+r)*NF + f] = (unsigned short)(pkrtz(v, 0.f) & 0xffffu);
                    }
                }
            }
        }
    }
}

// ---------------- GEMM2 (split-K): y += coef*(h @ W2[k] + b2[k]) ----------------
__global__ __launch_bounds__(256, 3) void k_gemm2(
    const unsigned short* __restrict__ hbuf, const float* __restrict__ W2,
    const float* __restrict__ b2, const int* __restrict__ wsi,
    const float* __restrict__ wsf, float* __restrict__ out, int pair_cap)
{
    __shared__ char lds[49152];
    __shared__ int stok[BM];
    __shared__ float scoef[BM];
    const int* seg  = wsi + WS_SEG;
    const int* tk   = wsi + WS_TILEK;
    const int* tr   = wsi + WS_TILER;
    const int* ptok = wsi + WS_PTOK;
    const float* pcoef = wsf + WS_PCOEF;
    int ntm = wsi[WS_NTILES];
    int nwork = ntm * (ND / BN) * SPLITK2;   // mt fastest, dt(16), sp(4)
    int tid  = threadIdx.x;
    int lane = tid & 63;
    int w    = tid >> 6;
    int wr = w >> 1, wc = w & 1;
    int l15 = lane & 15, q = lane >> 4;
    unsigned swzL = (unsigned)((l15 & 7) << 4);
    int arow = tid >> 1, ahalf = tid & 1;
    int bkq = tid >> 4, bcc = tid & 15;

    XCD_PART_LOOP(nwork){
        int widx = start_ + p_;
        int mt = widx % ntm;
        int rest = widx / ntm;
        int dt = rest & 15;
        int sp = rest >> 4;
        int kexp = tk[mt];
        int row0 = tr[mt];
        int nrows = min(BM, seg[kexp+1] - row0);
        int d0 = dt * BN;
        __syncthreads();
        if (tid < BM){
            int r = row0 + tid;
            bool v = (tid < nrows && r < pair_cap);
            stok[tid]  = v ? ptok[r] : 0;
            scoef[tid] = v ? pcoef[r] : 0.f;
        }
        __syncthreads();
        int hr = row0 + arow; if (hr >= pair_cap) hr = pair_cap - 1;
        const unsigned short* asrc = hbuf + (size_t)hr*NF + sp*(NF/SPLITK2) + ahalf*32;
        const float* bsrc = W2 + (size_t)kexp*NF*ND + (size_t)sp*(NF/SPLITK2)*ND + d0 + bcc*4;
        u32x4 ga0[4], ga1[4]; f32x4 gb0[4], gb1[4];
        LOAD_A(ga0, 0) LOAD_B(gb0, 0, ND)
        LOAD_A(ga1, 1) LOAD_B(gb1, 1, ND)
        f32x4 acc[4][2] = {};
        for (int t = 0; t < KT; t += 2){
            STAGE_A(ga0, AOFF0) STAGE_B(gb0, BOFF0)
            if (t + 2 < KT){ LOAD_A(ga0, t+2) LOAD_B(gb0, t+2, ND) }
            STEP_SYNC()
            MFMA_RD(AOFF0, BOFF0)
            STAGE_A(ga1, AOFF1) STAGE_B(gb1, BOFF1)
            if (t + 3 < KT){ LOAD_A(ga1, t+3) LOAD_B(gb1, t+3, ND) }
            STEP_SYNC()
            MFMA_RD(AOFF1, BOFF1)
        }
        const float* b2k = b2 + (size_t)kexp*ND;
        #pragma unroll
        for (int n = 0; n < 2; n++){
            int d = d0 + wc*32 + n*16 + l15;
            float bv = (sp == 0) ? b2k[d] : 0.f;
            #pragma unroll
            for (int m = 0; m < 4; m++){
                int rl = wr*64 + m*16 + q*4;
                #pragma unroll
                for (int i = 0; i < 4; i++){
                    int r = rl + i;
                    if (r < nrows && row0 + r < pair_cap){
                        float c = scoef[r];
                        atomicAdd(&out[(size_t)stok[r]*ND + d], c * (acc[m][n][i] + bv));
                    }
                }
            }
        }
    }
}

extern "C" void kernel_launch(void* const* d_in, const int* in_sizes, int n_in,
                              void* d_out, int out_size, void* d_ws, size_t ws_size,
                              hipStream_t stream)
{
    const float* x   = (const float*)d_in[0];
    const float* pl  = (const float*)d_in[1];
    const float* Wt  = (const float*)d_in[2];
    const float* Wgt = (const float*)d_in[3];
    const float* Wel = (const float*)d_in[4];
    const float* W1  = (const float*)d_in[5];
    const float* b1  = (const float*)d_in[6];
    const float* W2  = (const float*)d_in[7];
    const float* b2  = (const float*)d_in[8];
    float* out = (float*)d_out;
    int* wsi   = (int*)d_ws;
    float* wsf = (float*)d_ws;
    unsigned short* x16  = (unsigned short*)((char*)d_ws + (size_t)WS_X16*4);
    unsigned short* hbuf = (unsigned short*)((char*)d_ws + (size_t)WS_H*4);

    long long avail = (long long)ws_size - (long long)WS_H*4;
    long long cap = avail / ((long long)NF*2);
    if (cap > (long long)NTOK*NK) cap = (long long)NTOK*NK;
    if (cap < 0) cap = 0;
    int pair_cap = (int)cap;

    hipMemsetAsync(d_out, 0, (size_t)out_size*sizeof(float), stream);
    hipMemsetAsync(d_ws, 0, 32, stream);
    k_xcast<<<1024, 256, 0, stream>>>(x, x16);
    k_gating<<<NTOK, 256, 0, stream>>>(x, pl, Wt, Wgt, Wel, out, wsf + WS_COEF, wsi + WS_CNT);
    if (pair_cap > 0){
        k_scan<<<NK, 256, 0, stream>>>(wsf + WS_COEF, wsi, wsf, pair_cap);
        k_tiles<<<1, 64, 0, stream>>>(wsi, out, pair_cap);
        k_gemm1<<<2048, 256, 0, stream>>>(x16, W1, b1, wsi, hbuf, pair_cap);
        k_gemm2<<<2048, 256, 0, stream>>>(hbuf, W2, b2, wsi, wsf, out, pair_cap);
    }
}